// Round 1
// baseline (10619.974 us; speedup 1.0000x reference)
//
#include <hip/hip_runtime.h>
#include <hip/hip_bf16.h>
#include <math.h>

// ---- problem constants (from reference) ----
constexpr int SEQ   = 9 * 22 * 22;   // 4356
constexpr int DIM   = 1536;
constexpr int HEADS = 12;
constexpr int HD    = 128;
constexpr int CH    = 64;            // HD/2 (rope channels per head)
constexpr int C0c   = 22;
constexpr int C1c   = 21;
constexpr int WWc   = 22;
constexpr int HHWW  = 22 * 22;       // 484
constexpr int XS    = 484;           // h*w — keys used by attn map
constexpr size_t SD = (size_t)SEQ * DIM;

// ============================================================
// prep: zero attn_map region, compute mask counts
// ============================================================
__global__ __launch_bounds__(256) void prep_kernel(const float* __restrict__ mask,
                                                   float* __restrict__ amap,
                                                   float* __restrict__ cnt) {
  int t = threadIdx.x;
  for (int i = t; i < 2 * SEQ; i += 256) amap[i] = 0.f;
  float c0 = 0.f, c1 = 0.f;
  for (int i = t; i < XS; i += 256) { c0 += mask[i]; c1 += mask[XS + i]; }
  __shared__ float red0[256];
  __shared__ float red1[256];
  red0[t] = c0; red1[t] = c1;
  __syncthreads();
  for (int off = 128; off > 0; off >>= 1) {
    if (t < off) { red0[t] += red0[t + off]; red1[t] += red1[t + off]; }
    __syncthreads();
  }
  if (t == 0) { cnt[0] = red0[0]; cnt[1] = red1[0]; }
}

// ============================================================
// GEMM:  C[m][n] = sum_k A[m][k] * B[n][k] + bias[n]   (NT layout)
// N = K = DIM fixed. Tiled 64x64x32, f32, transposed LDS staging.
// ============================================================
__global__ __launch_bounds__(256) void gemm_bias(const float* __restrict__ A,
                                                 const float* __restrict__ B,
                                                 const float* __restrict__ bias,
                                                 float* __restrict__ C, int M) {
  constexpr int BM = 64, BN = 64, BK = 32;
  __shared__ __align__(16) float As[BK][BM + 4];  // [k][m], pad 68 floats
  __shared__ __align__(16) float Bs[BK][BN + 4];
  const int bm = blockIdx.x * BM;
  const int bn = blockIdx.y * BN;
  const int t  = threadIdx.x;
  const int tx = t & 15, ty = t >> 4;
  const int lr = t >> 3;            // 0..31 staging row
  const int lk = (t & 7) * 4;       // 0..28 staging k
  float acc[4][4] = {};
  for (int k0 = 0; k0 < DIM; k0 += BK) {
#pragma unroll
    for (int h = 0; h < 2; ++h) {
      const int r = lr + h * 32;
      const int ga = bm + r;
      float4 va = make_float4(0.f, 0.f, 0.f, 0.f);
      if (ga < M) va = *(const float4*)(A + (size_t)ga * DIM + k0 + lk);
      As[lk + 0][r] = va.x; As[lk + 1][r] = va.y;
      As[lk + 2][r] = va.z; As[lk + 3][r] = va.w;
      const int gb = bn + r;  // N multiple of 64 -> always valid
      float4 vb = *(const float4*)(B + (size_t)gb * DIM + k0 + lk);
      Bs[lk + 0][r] = vb.x; Bs[lk + 1][r] = vb.y;
      Bs[lk + 2][r] = vb.z; Bs[lk + 3][r] = vb.w;
    }
    __syncthreads();
#pragma unroll
    for (int kk = 0; kk < BK; ++kk) {
      const float4 a4 = *(const float4*)&As[kk][ty * 4];
      const float4 b4 = *(const float4*)&Bs[kk][tx * 4];
      const float av[4] = {a4.x, a4.y, a4.z, a4.w};
      const float bv[4] = {b4.x, b4.y, b4.z, b4.w};
#pragma unroll
      for (int i = 0; i < 4; ++i)
#pragma unroll
        for (int j = 0; j < 4; ++j)
          acc[i][j] = fmaf(av[i], bv[j], acc[i][j]);
    }
    __syncthreads();
  }
  const float4 b4 = *(const float4*)(bias + bn + tx * 4);
  const float bb[4] = {b4.x, b4.y, b4.z, b4.w};
#pragma unroll
  for (int i = 0; i < 4; ++i) {
    const int row = bm + ty * 4 + i;
    if (row >= M) continue;
    float4 w;
    w.x = acc[i][0] + bb[0]; w.y = acc[i][1] + bb[1];
    w.z = acc[i][2] + bb[2]; w.w = acc[i][3] + bb[3];
    *(float4*)(C + (size_t)row * DIM + bn + tx * 4) = w;
  }
}

// ============================================================
// RMSNorm (over full DIM) + RoPE (per head, 3D-grid tables), in place.
// scale is folded into the output (1/sqrt(HD) for q, 1.0 for k).
// ============================================================
__global__ __launch_bounds__(256) void rms_rope(float* __restrict__ y,
                                                const float* __restrict__ g,
                                                const float* __restrict__ fcos,
                                                const float* __restrict__ fsin,
                                                float scale) {
  const int s = blockIdx.x;
  float* row = y + (size_t)s * DIM;
  const int t = threadIdx.x;
  float ss = 0.f;
  for (int i = t; i < DIM; i += 256) { const float vv = row[i]; ss = fmaf(vv, vv, ss); }
#pragma unroll
  for (int off = 1; off < 64; off <<= 1) ss += __shfl_xor(ss, off);
  __shared__ float wred[4];
  if ((t & 63) == 0) wred[t >> 6] = ss;
  __syncthreads();
  const float tot = wred[0] + wred[1] + wred[2] + wred[3];
  const float rs = rsqrtf(tot * (1.0f / DIM) + 1e-6f);
  const int fi  = s / HHWW;
  const int rem = s - fi * HHWW;
  const int hi  = rem / WWc;
  const int wi  = rem - hi * WWc;
  for (int p = t; p < DIM / 2; p += 256) {
    const int head = p >> 6;
    const int c    = p & 63;
    const int idx  = head * HD + 2 * c;
    const int trow = (c < C0c) ? fi : ((c < C0c + C1c) ? hi : wi);
    const float co = fcos[trow * CH + c];
    const float si = fsin[trow * CH + c];
    const float a  = row[idx] * rs * g[idx];
    const float b  = row[idx + 1] * rs * g[idx + 1];
    row[idx]     = (a * co - b * si) * scale;
    row[idx + 1] = (a * si + b * co) * scale;
  }
}

// ============================================================
// Flash attention (f32) with fused attn-map over first XS keys.
// Block: 256 threads = (32 q-rows) x (8 lanes). One head per blockIdx.y.
// q is pre-scaled by 1/sqrt(HD).
// ============================================================
constexpr int QB = 32, KB = 32;
__global__ __launch_bounds__(256) void flash_attn(const float* __restrict__ q,
                                                  const float* __restrict__ k,
                                                  const float* __restrict__ v,
                                                  const float* __restrict__ mask,
                                                  const float* __restrict__ cnt,
                                                  float* __restrict__ o,
                                                  float* __restrict__ amap) {
  const int h  = blockIdx.y;
  const int q0 = blockIdx.x * QB;
  __shared__ __align__(16) float Qs[QB][HD + 4];
  __shared__ __align__(16) float Ks[KB][HD + 4];
  __shared__ __align__(16) float Vs[KB][HD + 4];
  __shared__ __align__(16) float Ps[QB][36];
  __shared__ float Msk0[KB];
  __shared__ float Msk1[KB];
  const int t  = threadIdx.x;
  const int r  = t >> 3;   // q-row in tile
  const int e  = t & 7;    // sub-lane: col group (S phase) / d-slice (PV phase)
  const int d0 = e * 16;
  {
    const int s = q0 + r;
#pragma unroll
    for (int j = 0; j < 4; ++j) {
      float4 vv = make_float4(0.f, 0.f, 0.f, 0.f);
      if (s < SEQ) vv = *(const float4*)(q + (size_t)s * DIM + h * HD + d0 + 4 * j);
      *(float4*)&Qs[r][d0 + 4 * j] = vv;
    }
  }
  float m_run = -1e30f, l_run = 0.f;
  float oacc[16] = {};
  float m2 = -1e30f, d2 = 0.f, n0 = 0.f, n1 = 0.f;
  constexpr int MAPT = (XS + KB - 1) / KB;  // 16 tiles feed the map
  const int ntiles = (SEQ + KB - 1) / KB;
  for (int tile = 0; tile < ntiles; ++tile) {
    const int kb = tile * KB;
    __syncthreads();  // previous PV done (and Q staged on first iter)
    {
      const int ks = kb + r;
      const float4 z = make_float4(0.f, 0.f, 0.f, 0.f);
      const bool ok = (ks < SEQ);
#pragma unroll
      for (int j = 0; j < 4; ++j) {
        *(float4*)&Ks[r][d0 + 4 * j] = ok ? *(const float4*)(k + (size_t)ks * DIM + h * HD + d0 + 4 * j) : z;
        *(float4*)&Vs[r][d0 + 4 * j] = ok ? *(const float4*)(v + (size_t)ks * DIM + h * HD + d0 + 4 * j) : z;
      }
      if (t < 2 * KB && tile < MAPT) {
        const int cc = t >> 5, kk = t & 31;
        const float mv = (kb + kk < XS) ? mask[cc * XS + kb + kk] : 0.f;
        if (cc == 0) Msk0[kk] = mv; else Msk1[kk] = mv;
      }
    }
    __syncthreads();
    // ---- S phase: S[r][4e+j] ----
    float sv[4] = {};
    for (int d = 0; d < HD; d += 4) {
      const float4 qv = *(const float4*)&Qs[r][d];
#pragma unroll
      for (int j = 0; j < 4; ++j) {
        const float4 kv = *(const float4*)&Ks[4 * e + j][d];
        sv[j] = fmaf(qv.x, kv.x, sv[j]);
        sv[j] = fmaf(qv.y, kv.y, sv[j]);
        sv[j] = fmaf(qv.z, kv.z, sv[j]);
        sv[j] = fmaf(qv.w, kv.w, sv[j]);
      }
    }
#pragma unroll
    for (int j = 0; j < 4; ++j) if (kb + 4 * e + j >= SEQ) sv[j] = -1e30f;
    float mt = fmaxf(fmaxf(sv[0], sv[1]), fmaxf(sv[2], sv[3]));
    mt = fmaxf(mt, __shfl_xor(mt, 1));
    mt = fmaxf(mt, __shfl_xor(mt, 2));
    mt = fmaxf(mt, __shfl_xor(mt, 4));
    const float m_new = fmaxf(m_run, mt);
    const float alpha = __expf(m_run - m_new);
    float pj[4], psum = 0.f;
#pragma unroll
    for (int j = 0; j < 4; ++j) { pj[j] = __expf(sv[j] - m_new); psum += pj[j]; }
    *(float4*)&Ps[r][4 * e] = make_float4(pj[0], pj[1], pj[2], pj[3]);
    psum += __shfl_xor(psum, 1);
    psum += __shfl_xor(psum, 2);
    psum += __shfl_xor(psum, 4);
    l_run = l_run * alpha + psum;
    m_run = m_new;
    // ---- fused attn-map accumulation over keys < XS ----
    if (tile < MAPT) {
      float lm = -1e30f;
#pragma unroll
      for (int j = 0; j < 4; ++j) if (kb + 4 * e + j < XS) lm = fmaxf(lm, sv[j]);
      const float m2n  = fmaxf(m2, lm);
      const float beta = __expf(m2 - m2n);
      d2 *= beta; n0 *= beta; n1 *= beta;
#pragma unroll
      for (int j = 0; j < 4; ++j) {
        if (kb + 4 * e + j < XS) {
          const float pe = __expf(sv[j] - m2n);
          d2 += pe;
          n0 = fmaf(pe, Msk0[4 * e + j], n0);
          n1 = fmaf(pe, Msk1[4 * e + j], n1);
        }
      }
      m2 = m2n;
    }
    __syncthreads();  // Ps ready, Ks consumed
    // ---- PV phase: thread (r, e) owns d-slice d0..d0+15 ----
#pragma unroll
    for (int x = 0; x < 16; ++x) oacc[x] *= alpha;
    for (int c = 0; c < KB; ++c) {
      const float p = Ps[r][c];
#pragma unroll
      for (int j = 0; j < 4; ++j) {
        const float4 vv = *(const float4*)&Vs[c][d0 + 4 * j];
        oacc[4 * j + 0] = fmaf(p, vv.x, oacc[4 * j + 0]);
        oacc[4 * j + 1] = fmaf(p, vv.y, oacc[4 * j + 1]);
        oacc[4 * j + 2] = fmaf(p, vv.z, oacc[4 * j + 2]);
        oacc[4 * j + 3] = fmaf(p, vv.w, oacc[4 * j + 3]);
      }
    }
  }
  // ---- epilogue: O write ----
  const int s = q0 + r;
  if (s < SEQ) {
    const float inv = 1.f / l_run;
#pragma unroll
    for (int j = 0; j < 4; ++j) {
      float4 vv;
      vv.x = oacc[4 * j + 0] * inv; vv.y = oacc[4 * j + 1] * inv;
      vv.z = oacc[4 * j + 2] * inv; vv.w = oacc[4 * j + 3] * inv;
      *(float4*)(o + (size_t)s * DIM + h * HD + d0 + 4 * j) = vv;
    }
  }
  // ---- attn-map: combine the 8 lanes of this row, one atomic per row ----
#pragma unroll
  for (int off = 1; off < 8; off <<= 1) {
    const float om = __shfl_xor(m2, off);
    const float od = __shfl_xor(d2, off);
    const float o0 = __shfl_xor(n0, off);
    const float o1 = __shfl_xor(n1, off);
    const float mm = fmaxf(m2, om);
    const float sa = __expf(m2 - mm);
    const float sb = __expf(om - mm);
    d2 = d2 * sa + od * sb;
    n0 = n0 * sa + o0 * sb;
    n1 = n1 * sa + o1 * sb;
    m2 = mm;
  }
  if (e == 0 && s < SEQ) {
    const float invd = 1.f / (d2 * (float)HEADS);
    atomicAdd(&amap[s],       n0 * invd / cnt[0]);
    atomicAdd(&amap[SEQ + s], n1 * invd / cnt[1]);
  }
}

// ============================================================
extern "C" void kernel_launch(void* const* d_in, const int* in_sizes, int n_in,
                              void* d_out, int out_size, void* d_ws, size_t ws_size,
                              hipStream_t stream) {
  const float* x    = (const float*)d_in[0];
  const float* Wq   = (const float*)d_in[1];
  const float* bq   = (const float*)d_in[2];
  const float* Wk   = (const float*)d_in[3];
  const float* bk   = (const float*)d_in[4];
  const float* Wv   = (const float*)d_in[5];
  const float* bv   = (const float*)d_in[6];
  const float* Wo   = (const float*)d_in[7];
  const float* bo   = (const float*)d_in[8];
  const float* gq   = (const float*)d_in[9];
  const float* gk   = (const float*)d_in[10];
  const float* fc   = (const float*)d_in[11];
  const float* fs   = (const float*)d_in[12];
  const float* mask = (const float*)d_in[13];

  float* out  = (float*)d_out;
  float* amap = out + SD;

  float* qb  = (float*)d_ws;
  float* kb  = qb + SD;
  float* vb  = kb + SD;
  float* ob  = vb + SD;
  float* cnt = ob + SD;

  prep_kernel<<<1, 256, 0, stream>>>(mask, amap, cnt);

  dim3 gg((SEQ + 63) / 64, DIM / 64);
  gemm_bias<<<gg, 256, 0, stream>>>(x, Wq, bq, qb, SEQ);
  gemm_bias<<<gg, 256, 0, stream>>>(x, Wk, bk, kb, SEQ);
  gemm_bias<<<gg, 256, 0, stream>>>(x, Wv, bv, vb, SEQ);

  const float scale = 0.08838834764831845f;  // 1/sqrt(128)
  rms_rope<<<SEQ, 256, 0, stream>>>(qb, gq, fc, fs, scale);
  rms_rope<<<SEQ, 256, 0, stream>>>(kb, gk, fc, fs, 1.0f);

  dim3 fg((SEQ + QB - 1) / QB, HEADS);
  flash_attn<<<fg, 256, 0, stream>>>(qb, kb, vb, mask, cnt, ob, amap);

  gemm_bias<<<gg, 256, 0, stream>>>(ob, Wo, bo, out, SEQ);
}

// Round 2
// 1232.518 us; speedup vs baseline: 8.6165x; 8.6165x over previous
//
#include <hip/hip_runtime.h>
#include <hip/hip_bf16.h>
#include <math.h>

// ---- problem constants ----
constexpr int SEQ   = 4356;
constexpr int DIM   = 1536;
constexpr int HEADS = 12;
constexpr int HD    = 128;
constexpr int CH    = 64;           // HD/2 rope channels
constexpr int C0c   = 22;
constexpr int C1c   = 21;
constexpr int WWc   = 22;
constexpr int HHWW  = 484;
constexpr int XS    = 484;
constexpr int SEQP  = 4384;         // padded V^T row pitch (>= 4352+32)
constexpr size_t SD = (size_t)SEQ * DIM;

typedef float f32x4 __attribute__((ext_vector_type(4)));
typedef short bf16x8 __attribute__((ext_vector_type(8)));
typedef short bf16x4 __attribute__((ext_vector_type(4)));

__device__ inline unsigned short f2bf(float f) {
  union { float f; unsigned u; } x; x.f = f;
  return (unsigned short)((x.u + 0x7FFFu + ((x.u >> 16) & 1u)) >> 16);
}

#define GLD16(g, l)                                                                        \
  __builtin_amdgcn_global_load_lds((const __attribute__((address_space(1))) unsigned*)    \
                                       (const void*)(g),                                  \
                                   (__attribute__((address_space(3))) unsigned*)(void*)(l),\
                                   16, 0, 0)

// ============================================================
// prep: zero attn-map region, mask counts
// ============================================================
__global__ __launch_bounds__(256) void prep_kernel(const float* __restrict__ mask,
                                                   float* __restrict__ amap,
                                                   float* __restrict__ cnt) {
  int t = threadIdx.x;
  for (int i = t; i < 2 * SEQ; i += 256) amap[i] = 0.f;
  float c0 = 0.f, c1 = 0.f;
  for (int i = t; i < XS; i += 256) { c0 += mask[i]; c1 += mask[XS + i]; }
  __shared__ float red0[256];
  __shared__ float red1[256];
  red0[t] = c0; red1[t] = c1;
  __syncthreads();
  for (int off = 128; off > 0; off >>= 1) {
    if (t < off) { red0[t] += red0[t + off]; red1[t] += red1[t + off]; }
    __syncthreads();
  }
  if (t == 0) { cnt[0] = red0[0]; cnt[1] = red1[0]; }
}

// zero the V^T tail columns (keys SEQ..SEQP) so PV reads finite data
__global__ __launch_bounds__(256) void padzero(unsigned short* __restrict__ vt) {
  const int pad = SEQP - SEQ;                  // 28
  const int total = DIM * pad;
  for (int i = blockIdx.x * 256 + threadIdx.x; i < total; i += gridDim.x * 256) {
    const int d = i / pad, c = i - d * pad;
    vt[(size_t)d * SEQP + SEQ + c] = 0;
  }
}

// f32 -> bf16 (RNE), vectorized
__global__ __launch_bounds__(256) void to_bf16(const float* __restrict__ in,
                                               unsigned short* __restrict__ out, int n4) {
  for (int i = blockIdx.x * 256 + threadIdx.x; i < n4; i += gridDim.x * 256) {
    const float4 v = ((const float4*)in)[i];
    ushort4 o;
    o.x = f2bf(v.x); o.y = f2bf(v.y); o.z = f2bf(v.z); o.w = f2bf(v.w);
    ((ushort4*)out)[i] = o;
  }
}

// ============================================================
// MFMA GEMM (NT): C[m][n] = sum_k A[m][k]*B[n][k] + bias[n]
// A: [M x 1536] bf16, B: [1536 x 1536] bf16. 128x128 tile, BK=64.
// OMODE 0: f32 row-major out. OMODE 2: bf16 transposed out (pitch SEQP).
// ============================================================
template <int OMODE>
__global__ __launch_bounds__(256) void gemm_mfma(const unsigned short* __restrict__ A,
                                                 const unsigned short* __restrict__ B,
                                                 const float* __restrict__ bias,
                                                 void* __restrict__ Cv, int M) {
  __shared__ unsigned short As[128 * 64];
  __shared__ unsigned short Bs[128 * 64];
  const int t    = threadIdx.x;
  const int lane = t & 63;
  const int w    = t >> 6;
  const int wr   = w >> 1, wc = w & 1;
  const int bm = blockIdx.x * 128, bn = blockIdx.y * 128;
  const int lq = lane & 15, lg = lane >> 4;
  f32x4 acc[4][4] = {};
  for (int k0 = 0; k0 < DIM; k0 += 64) {
#pragma unroll
    for (int i = 0; i < 4; ++i) {
      const int idx = i * 256 + t;       // 16B chunk id, 8 chunks/row
      const int row = idx >> 3;
      const int c8  = (idx & 7) * 8;
      const int ga  = min(bm + row, M - 1);
      GLD16(A + (size_t)ga * DIM + k0 + c8, As + idx * 8);
      const int gb  = bn + row;          // N=1536 divides by 128
      GLD16(B + (size_t)gb * DIM + k0 + c8, Bs + idx * 8);
    }
    __syncthreads();
#pragma unroll
    for (int kk = 0; kk < 2; ++kk) {
      bf16x8 af[4], bf[4];
#pragma unroll
      for (int m = 0; m < 4; ++m)
        af[m] = *(const bf16x8*)(As + (wr * 64 + m * 16 + lq) * 64 + kk * 32 + lg * 8);
#pragma unroll
      for (int n = 0; n < 4; ++n)
        bf[n] = *(const bf16x8*)(Bs + (wc * 64 + n * 16 + lq) * 64 + kk * 32 + lg * 8);
#pragma unroll
      for (int m = 0; m < 4; ++m)
#pragma unroll
        for (int n = 0; n < 4; ++n)
          acc[m][n] = __builtin_amdgcn_mfma_f32_16x16x32_bf16(af[m], bf[n], acc[m][n], 0, 0, 0);
    }
    __syncthreads();
  }
  // epilogue: lane holds col = 16-frag col + lq, rows = lg*4 + reg
#pragma unroll
  for (int n = 0; n < 4; ++n) {
    const int col = bn + wc * 64 + n * 16 + lq;
    const float bv = bias[col];
#pragma unroll
    for (int m = 0; m < 4; ++m) {
      const int rm = bm + wr * 64 + m * 16 + lg * 4;
      if (OMODE == 0) {
        float* C = (float*)Cv;
#pragma unroll
        for (int r = 0; r < 4; ++r) {
          const int row = rm + r;
          if (row < M) C[(size_t)row * DIM + col] = acc[m][n][r] + bv;
        }
      } else {
        unsigned short* C = (unsigned short*)Cv;   // C^T, pitch SEQP (M%4==0)
        if (rm < M) {
          bf16x4 o;
#pragma unroll
          for (int r = 0; r < 4; ++r) o[r] = (short)f2bf(acc[m][n][r] + bv);
          *(bf16x4*)(C + (size_t)col * SEQP + rm) = o;
        }
      }
    }
  }
}

// ============================================================
// RMSNorm + RoPE, f32 in -> bf16 out (scale folded into output)
// ============================================================
__global__ __launch_bounds__(256) void rms_rope_b(const float* __restrict__ y,
                                                  const float* __restrict__ g,
                                                  const float* __restrict__ fcos,
                                                  const float* __restrict__ fsin,
                                                  float scale,
                                                  unsigned short* __restrict__ outb) {
  const int s = blockIdx.x;
  const float* row = y + (size_t)s * DIM;
  const int t = threadIdx.x;
  float ss = 0.f;
  for (int i = t; i < DIM / 4; i += 256) {
    const float4 v = ((const float4*)row)[i];
    ss += v.x * v.x + v.y * v.y + v.z * v.z + v.w * v.w;
  }
#pragma unroll
  for (int off = 1; off < 64; off <<= 1) ss += __shfl_xor(ss, off);
  __shared__ float wred[4];
  if ((t & 63) == 0) wred[t >> 6] = ss;
  __syncthreads();
  const float tot = wred[0] + wred[1] + wred[2] + wred[3];
  const float rs = rsqrtf(tot * (1.0f / DIM) + 1e-6f);
  const int fi  = s / HHWW;
  const int rem = s - fi * HHWW;
  const int hi  = rem / WWc;
  const int wi  = rem - hi * WWc;
  for (int p = t; p < DIM / 2; p += 256) {
    const int head = p >> 6;
    const int c    = p & 63;
    const int idx  = head * HD + 2 * c;
    const int trow = (c < C0c) ? fi : ((c < C0c + C1c) ? hi : wi);
    const float co = fcos[trow * CH + c];
    const float si = fsin[trow * CH + c];
    const float a  = row[idx] * rs * g[idx];
    const float b  = row[idx + 1] * rs * g[idx + 1];
    ushort2 pr;
    pr.x = f2bf((a * co - b * si) * scale);
    pr.y = f2bf((a * si + b * co) * scale);
    *(ushort2*)(outb + (size_t)s * DIM + idx) = pr;
  }
}

// ============================================================
// MFMA flash attention + fused attn-map.
// Block: 4 waves; wave w owns 16 q-rows (q0 = bx*64 + w*16), head = by.
// S^T = K·Q^T via mfma(kfrag, qfrag): lane -> one q-col, 8 key-rows.
// P round-trips through wave-private LDS; PV: acc[d][q] += V^T-frag · P-frag.
// ============================================================
__global__ __launch_bounds__(256) void flash_mfma(const unsigned short* __restrict__ qb,
                                                  const unsigned short* __restrict__ kbuf,
                                                  const unsigned short* __restrict__ vt,
                                                  const float* __restrict__ mask,
                                                  const float* __restrict__ cnt,
                                                  unsigned short* __restrict__ ob,
                                                  float* __restrict__ amap) {
  const int h    = blockIdx.y;
  const int w    = threadIdx.x >> 6;
  const int lane = threadIdx.x & 63;
  const int lq   = lane & 15, lg = lane >> 4;
  const int qrow = blockIdx.x * 64 + w * 16 + lq;
  const int qsrc = min(qrow, SEQ - 1);
  __shared__ unsigned short Plds[4][16][40];   // per-wave P tile, pitch 40
  unsigned short (*P)[40] = Plds[w];

  bf16x8 qf[4];
#pragma unroll
  for (int c = 0; c < 4; ++c)
    qf[c] = *(const bf16x8*)(qb + (size_t)qsrc * DIM + h * HD + c * 32 + lg * 8);

  const unsigned short* kh = kbuf + h * HD;
  const unsigned short* vh = vt + (size_t)(h * HD) * SEQP;

  f32x4 acc[8] = {};
  float m_run = -1e30f, l_run = 0.f;
  float m2 = -1e30f, d2 = 0.f, n0 = 0.f, n1 = 0.f;

  for (int kb = 0; kb < SEQ; kb += 32) {
    // ---- S^T = K . Q^T ----
    f32x4 sacc[2] = {};
#pragma unroll
    for (int kbi = 0; kbi < 2; ++kbi) {
      const int krow = min(kb + kbi * 16 + lq, SEQ - 1);
      const unsigned short* kp = kh + (size_t)krow * DIM;
#pragma unroll
      for (int c = 0; c < 4; ++c) {
        const bf16x8 kf = *(const bf16x8*)(kp + c * 32 + lg * 8);
        sacc[kbi] = __builtin_amdgcn_mfma_f32_16x16x32_bf16(kf, qf[c], sacc[kbi], 0, 0, 0);
      }
    }
    float s[8];
    float mt = -1e30f;
#pragma unroll
    for (int kbi = 0; kbi < 2; ++kbi)
#pragma unroll
      for (int r = 0; r < 4; ++r) {
        const int key = kb + kbi * 16 + lg * 4 + r;
        float v = sacc[kbi][r];
        if (key >= SEQ) v = -1e30f;
        s[kbi * 4 + r] = v;
        mt = fmaxf(mt, v);
      }
    mt = fmaxf(mt, __shfl_xor(mt, 16));
    mt = fmaxf(mt, __shfl_xor(mt, 32));
    const float m_new = fmaxf(m_run, mt);
    const float alpha = __expf(m_run - m_new);
    float p[8], ps = 0.f;
#pragma unroll
    for (int i = 0; i < 8; ++i) { p[i] = __expf(s[i] - m_new); ps += p[i]; }
    ps += __shfl_xor(ps, 16);
    ps += __shfl_xor(ps, 32);
    l_run = l_run * alpha + ps;
    m_run = m_new;

    // ---- fused attn-map over keys < XS (lane-local online state) ----
    if (kb < XS) {
      float lm = -1e30f;
#pragma unroll
      for (int i = 0; i < 8; ++i) {
        const int key = kb + (i >> 2) * 16 + lg * 4 + (i & 3);
        if (key < XS) lm = fmaxf(lm, s[i]);
      }
      const float m2n  = fmaxf(m2, lm);
      const float beta = __expf(m2 - m2n);
      d2 *= beta; n0 *= beta; n1 *= beta;
      m2 = m2n;
#pragma unroll
      for (int i = 0; i < 8; ++i) {
        const int key = kb + (i >> 2) * 16 + lg * 4 + (i & 3);
        if (key < XS) {
          const float pe = __expf(s[i] - m2);
          d2 += pe;
          n0 = fmaf(pe, mask[key], n0);
          n1 = fmaf(pe, mask[XS + key], n1);
        }
      }
    }

    // ---- write P (bf16) to wave-private LDS ----
#pragma unroll
    for (int kbi = 0; kbi < 2; ++kbi) {
      bf16x4 pb;
#pragma unroll
      for (int r = 0; r < 4; ++r) pb[r] = (short)f2bf(p[kbi * 4 + r]);
      *(bf16x4*)&P[lq][kbi * 16 + lg * 4] = pb;
    }

    // ---- rescale O accumulator ----
#pragma unroll
    for (int db = 0; db < 8; ++db) {
      acc[db][0] *= alpha; acc[db][1] *= alpha;
      acc[db][2] *= alpha; acc[db][3] *= alpha;
    }

    // ---- PV: acc[d][q] += V^T . P ----
    const bf16x8 pf = *(const bf16x8*)&P[lq][lg * 8];
#pragma unroll
    for (int db = 0; db < 8; ++db) {
      const bf16x8 vf = *(const bf16x8*)(vh + (size_t)(db * 16 + lq) * SEQP + kb + lg * 8);
      acc[db] = __builtin_amdgcn_mfma_f32_16x16x32_bf16(vf, pf, acc[db], 0, 0, 0);
    }
  }

  // ---- epilogue: O write (bf16, transposed back to row-major) ----
  if (qrow < SEQ) {
    const float inv = 1.f / l_run;
#pragma unroll
    for (int db = 0; db < 8; ++db) {
      bf16x4 o;
#pragma unroll
      for (int r = 0; r < 4; ++r) o[r] = (short)f2bf(acc[db][r] * inv);
      *(bf16x4*)(ob + (size_t)qrow * DIM + h * HD + db * 16 + lg * 4) = o;
    }
  }

  // ---- attn-map: merge the 4 replicas (lane groups) per q ----
#pragma unroll
  for (int off = 16; off <= 32; off <<= 1) {
    const float om = __shfl_xor(m2, off);
    const float od = __shfl_xor(d2, off);
    const float o0 = __shfl_xor(n0, off);
    const float o1 = __shfl_xor(n1, off);
    const float mm = fmaxf(m2, om);
    const float sa = __expf(m2 - mm);
    const float sb = __expf(om - mm);
    d2 = d2 * sa + od * sb;
    n0 = n0 * sa + o0 * sb;
    n1 = n1 * sa + o1 * sb;
    m2 = mm;
  }
  if (lane < 16 && qrow < SEQ) {
    const float invd = 1.f / (d2 * (float)HEADS);
    atomicAdd(&amap[qrow],       n0 * invd / cnt[0]);
    atomicAdd(&amap[SEQ + qrow], n1 * invd / cnt[1]);
  }
}

// ============================================================
extern "C" void kernel_launch(void* const* d_in, const int* in_sizes, int n_in,
                              void* d_out, int out_size, void* d_ws, size_t ws_size,
                              hipStream_t stream) {
  const float* x    = (const float*)d_in[0];
  const float* Wq   = (const float*)d_in[1];
  const float* bq   = (const float*)d_in[2];
  const float* Wk   = (const float*)d_in[3];
  const float* bk   = (const float*)d_in[4];
  const float* Wv   = (const float*)d_in[5];
  const float* bv   = (const float*)d_in[6];
  const float* Wo   = (const float*)d_in[7];
  const float* bo   = (const float*)d_in[8];
  const float* gq   = (const float*)d_in[9];
  const float* gk   = (const float*)d_in[10];
  const float* fc   = (const float*)d_in[11];
  const float* fs   = (const float*)d_in[12];
  const float* mask = (const float*)d_in[13];

  float* out  = (float*)d_out;
  float* amap = out + SD;

  float* f32tmp      = (float*)d_ws;                    // SD f32
  unsigned short* xb = (unsigned short*)(f32tmp + SD);  // SD bf16
  unsigned short* qb = xb + SD;
  unsigned short* kb = qb + SD;
  unsigned short* vt = kb + SD;                         // DIM*SEQP bf16
  unsigned short* ob = vt + (size_t)DIM * SEQP;
  unsigned short* wb = ob + SD;                         // DIM*DIM bf16
  float* cnt = (float*)(wb + (size_t)DIM * DIM);

  prep_kernel<<<1, 256, 0, stream>>>(mask, amap, cnt);
  padzero<<<32, 256, 0, stream>>>(vt);
  to_bf16<<<2048, 256, 0, stream>>>(x, xb, (int)(SD / 4));

  const dim3 gg((SEQ + 127) / 128, DIM / 128);
  constexpr int W4 = DIM * DIM / 4;

  // V projection -> V^T bf16
  to_bf16<<<1024, 256, 0, stream>>>(Wv, wb, W4);
  gemm_mfma<2><<<gg, 256, 0, stream>>>(xb, wb, bv, vt, SEQ);

  const float scale = 0.08838834764831845f;  // 1/sqrt(128)
  // Q projection -> rms+rope -> bf16 (scale folded)
  to_bf16<<<1024, 256, 0, stream>>>(Wq, wb, W4);
  gemm_mfma<0><<<gg, 256, 0, stream>>>(xb, wb, bq, f32tmp, SEQ);
  rms_rope_b<<<SEQ, 256, 0, stream>>>(f32tmp, gq, fc, fs, scale, qb);
  // K projection -> rms+rope -> bf16
  to_bf16<<<1024, 256, 0, stream>>>(Wk, wb, W4);
  gemm_mfma<0><<<gg, 256, 0, stream>>>(xb, wb, bk, f32tmp, SEQ);
  rms_rope_b<<<SEQ, 256, 0, stream>>>(f32tmp, gk, fc, fs, 1.0f, kb);

  // attention + attn-map
  const dim3 fg((SEQ + 63) / 64, HEADS);
  flash_mfma<<<fg, 256, 0, stream>>>(qb, kb, vt, mask, cnt, ob, amap);

  // output projection (f32 out)
  to_bf16<<<1024, 256, 0, stream>>>(Wo, wb, W4);
  gemm_mfma<0><<<gg, 256, 0, stream>>>(ob, wb, bo, out, SEQ);
}

// Round 3
// 569.175 us; speedup vs baseline: 18.6586x; 2.1654x over previous
//
#include <hip/hip_runtime.h>
#include <hip/hip_bf16.h>
#include <math.h>

// ---- problem constants ----
constexpr int SEQ   = 4356;
constexpr int DIM   = 1536;
constexpr int HEADS = 12;
constexpr int HD    = 128;
constexpr int CH    = 64;           // HD/2 rope channels
constexpr int C0c   = 22;
constexpr int C1c   = 21;
constexpr int WWc   = 22;
constexpr int HHWW  = 484;
constexpr int XS    = 484;
constexpr int KVB   = 64;
constexpr int NT    = (SEQ + KVB - 1) / KVB;   // 69 tiles
constexpr int SEQP  = NT * KVB;                // 4416 padded V^T pitch
constexpr size_t SD = (size_t)SEQ * DIM;

typedef float f32x4 __attribute__((ext_vector_type(4)));
typedef short bf16x8 __attribute__((ext_vector_type(8)));
typedef short bf16x4 __attribute__((ext_vector_type(4)));

__device__ inline unsigned short f2bf(float f) {
  union { float f; unsigned u; } x; x.f = f;
  return (unsigned short)((x.u + 0x7FFFu + ((x.u >> 16) & 1u)) >> 16);
}

#define GLD16(g, l)                                                                        \
  __builtin_amdgcn_global_load_lds((const __attribute__((address_space(1))) unsigned*)    \
                                       (const void*)(g),                                  \
                                   (__attribute__((address_space(3))) unsigned*)(void*)(l),\
                                   16, 0, 0)

// ============================================================
// prep: zero attn-map region, mask counts
// ============================================================
__global__ __launch_bounds__(256) void prep_kernel(const float* __restrict__ mask,
                                                   float* __restrict__ amap,
                                                   float* __restrict__ cnt) {
  int t = threadIdx.x;
  for (int i = t; i < 2 * SEQ; i += 256) amap[i] = 0.f;
  float c0 = 0.f, c1 = 0.f;
  for (int i = t; i < XS; i += 256) { c0 += mask[i]; c1 += mask[XS + i]; }
  __shared__ float red0[256];
  __shared__ float red1[256];
  red0[t] = c0; red1[t] = c1;
  __syncthreads();
  for (int off = 128; off > 0; off >>= 1) {
    if (t < off) { red0[t] += red0[t + off]; red1[t] += red1[t + off]; }
    __syncthreads();
  }
  if (t == 0) { cnt[0] = red0[0]; cnt[1] = red1[0]; }
}

// zero the V^T tail columns (keys SEQ..SEQP)
__global__ __launch_bounds__(256) void padzero(unsigned short* __restrict__ vt) {
  const int pad = SEQP - SEQ;                  // 60
  const int total = DIM * pad;
  for (int i = blockIdx.x * 256 + threadIdx.x; i < total; i += gridDim.x * 256) {
    const int d = i / pad, c = i - d * pad;
    vt[(size_t)d * SEQP + SEQ + c] = 0;
  }
}

// f32 -> bf16 (RNE), vectorized
__global__ __launch_bounds__(256) void to_bf16(const float* __restrict__ in,
                                               unsigned short* __restrict__ out, int n4) {
  for (int i = blockIdx.x * 256 + threadIdx.x; i < n4; i += gridDim.x * 256) {
    const float4 v = ((const float4*)in)[i];
    ushort4 o;
    o.x = f2bf(v.x); o.y = f2bf(v.y); o.z = f2bf(v.z); o.w = f2bf(v.w);
    ((ushort4*)out)[i] = o;
  }
}

// ============================================================
// MFMA GEMM (NT): C[m][n] = sum_k A[m][k]*B[n][k] + bias[n]
// OMODE 0: f32 row-major out. OMODE 2: bf16 transposed out (pitch SEQP).
// ============================================================
template <int OMODE>
__global__ __launch_bounds__(256) void gemm_mfma(const unsigned short* __restrict__ A,
                                                 const unsigned short* __restrict__ B,
                                                 const float* __restrict__ bias,
                                                 void* __restrict__ Cv, int M) {
  __shared__ unsigned short As[128 * 64];
  __shared__ unsigned short Bs[128 * 64];
  const int t    = threadIdx.x;
  const int lane = t & 63;
  const int w    = t >> 6;
  const int wr   = w >> 1, wc = w & 1;
  const int bm = blockIdx.x * 128, bn = blockIdx.y * 128;
  const int lq = lane & 15, lg = lane >> 4;
  f32x4 acc[4][4] = {};
  for (int k0 = 0; k0 < DIM; k0 += 64) {
#pragma unroll
    for (int i = 0; i < 4; ++i) {
      const int idx = i * 256 + t;       // 16B chunk id, 8 chunks/row
      const int row = idx >> 3;
      const int c8  = (idx & 7) * 8;
      const int ga  = min(bm + row, M - 1);
      GLD16(A + (size_t)ga * DIM + k0 + c8, As + idx * 8);
      const int gb  = bn + row;
      GLD16(B + (size_t)gb * DIM + k0 + c8, Bs + idx * 8);
    }
    __syncthreads();
#pragma unroll
    for (int kk = 0; kk < 2; ++kk) {
      bf16x8 af[4], bf[4];
#pragma unroll
      for (int m = 0; m < 4; ++m)
        af[m] = *(const bf16x8*)(As + (wr * 64 + m * 16 + lq) * 64 + kk * 32 + lg * 8);
#pragma unroll
      for (int n = 0; n < 4; ++n)
        bf[n] = *(const bf16x8*)(Bs + (wc * 64 + n * 16 + lq) * 64 + kk * 32 + lg * 8);
#pragma unroll
      for (int m = 0; m < 4; ++m)
#pragma unroll
        for (int n = 0; n < 4; ++n)
          acc[m][n] = __builtin_amdgcn_mfma_f32_16x16x32_bf16(af[m], bf[n], acc[m][n], 0, 0, 0);
    }
    __syncthreads();
  }
#pragma unroll
  for (int n = 0; n < 4; ++n) {
    const int col = bn + wc * 64 + n * 16 + lq;
    const float bv = bias[col];
#pragma unroll
    for (int m = 0; m < 4; ++m) {
      const int rm = bm + wr * 64 + m * 16 + lg * 4;
      if (OMODE == 0) {
        float* C = (float*)Cv;
#pragma unroll
        for (int r = 0; r < 4; ++r) {
          const int row = rm + r;
          if (row < M) C[(size_t)row * DIM + col] = acc[m][n][r] + bv;
        }
      } else {
        unsigned short* C = (unsigned short*)Cv;   // C^T, pitch SEQP
        if (rm < M) {
          bf16x4 o;
#pragma unroll
          for (int r = 0; r < 4; ++r) o[r] = (short)f2bf(acc[m][n][r] + bv);
          *(bf16x4*)(C + (size_t)col * SEQP + rm) = o;
        }
      }
    }
  }
}

// ============================================================
// RMSNorm + RoPE, f32 in -> bf16 out (scale folded into output)
// ============================================================
__global__ __launch_bounds__(256) void rms_rope_b(const float* __restrict__ y,
                                                  const float* __restrict__ g,
                                                  const float* __restrict__ fcos,
                                                  const float* __restrict__ fsin,
                                                  float scale,
                                                  unsigned short* __restrict__ outb) {
  const int s = blockIdx.x;
  const float* row = y + (size_t)s * DIM;
  const int t = threadIdx.x;
  float ss = 0.f;
  for (int i = t; i < DIM / 4; i += 256) {
    const float4 v = ((const float4*)row)[i];
    ss += v.x * v.x + v.y * v.y + v.z * v.z + v.w * v.w;
  }
#pragma unroll
  for (int off = 1; off < 64; off <<= 1) ss += __shfl_xor(ss, off);
  __shared__ float wred[4];
  if ((t & 63) == 0) wred[t >> 6] = ss;
  __syncthreads();
  const float tot = wred[0] + wred[1] + wred[2] + wred[3];
  const float rs = rsqrtf(tot * (1.0f / DIM) + 1e-6f);
  const int fi  = s / HHWW;
  const int rem = s - fi * HHWW;
  const int hi  = rem / WWc;
  const int wi  = rem - hi * WWc;
  for (int p = t; p < DIM / 2; p += 256) {
    const int head = p >> 6;
    const int c    = p & 63;
    const int idx  = head * HD + 2 * c;
    const int trow = (c < C0c) ? fi : ((c < C0c + C1c) ? hi : wi);
    const float co = fcos[trow * CH + c];
    const float si = fsin[trow * CH + c];
    const float a  = row[idx] * rs * g[idx];
    const float b  = row[idx + 1] * rs * g[idx + 1];
    ushort2 pr;
    pr.x = f2bf((a * co - b * si) * scale);
    pr.y = f2bf((a * si + b * co) * scale);
    *(ushort2*)(outb + (size_t)s * DIM + idx) = pr;
  }
}

// ============================================================
// Flash attention v2: KVB=64 K/V tiles staged in LDS (XOR-swizzled),
// shared by 4 waves; reg-prefetch of next tile (T14); 32 q-rows/wave.
// ============================================================
__global__ __launch_bounds__(256) void flash_mfma(const unsigned short* __restrict__ qb,
                                                  const unsigned short* __restrict__ kbuf,
                                                  const unsigned short* __restrict__ vt,
                                                  const float* __restrict__ mask,
                                                  const float* __restrict__ cnt,
                                                  unsigned short* __restrict__ ob,
                                                  float* __restrict__ amap) {
  const int h    = blockIdx.y;
  const int t    = threadIdx.x;
  const int w    = t >> 6;
  const int lane = t & 63;
  const int lq   = lane & 15, lg = lane >> 4;
  const int qbase = blockIdx.x * 128 + w * 32;

  __shared__ unsigned short Ks[64 * 128];       // [key][dim], swizzled 16B slots
  __shared__ unsigned short Vs[128 * 64];       // [dim][key], swizzled 16B slots
  __shared__ unsigned short Plds[4][32][72];    // per-wave P, pitch 72
  unsigned short (*P)[72] = Plds[w];

  const unsigned short* kh = kbuf + h * HD;
  const unsigned short* vh = vt + (size_t)(h * HD) * SEQP;

  // Q fragments for both q-sets (scale already folded into q)
  bf16x8 qf[2][4];
#pragma unroll
  for (int qs = 0; qs < 2; ++qs) {
    const int qsrc = min(qbase + qs * 16 + lq, SEQ - 1);
#pragma unroll
    for (int c = 0; c < 4; ++c)
      qf[qs][c] = *(const bf16x8*)(qb + (size_t)qsrc * DIM + h * HD + c * 32 + lg * 8);
  }

  f32x4 acc[2][8] = {};
  float m_run[2] = {-1e30f, -1e30f}, l_run[2] = {0.f, 0.f};
  float m2[2] = {-1e30f, -1e30f}, d2[2] = {0.f, 0.f}, n0[2] = {0.f, 0.f}, n1[2] = {0.f, 0.f};

  bf16x8 stK[4], stV[4];
  // ---- prologue: stage tile 0 ----
#pragma unroll
  for (int j = 0; j < 4; ++j) {
    const int ck = t + j * 256;
    const int kr = ck >> 4, ks = ck & 15;
    stK[j] = *(const bf16x8*)(kh + (size_t)min(kr, SEQ - 1) * DIM + ks * 8);
    const int vd = ck >> 3, vs = ck & 7;
    stV[j] = *(const bf16x8*)(vh + (size_t)vd * SEQP + vs * 8);
  }
#pragma unroll
  for (int j = 0; j < 4; ++j) {
    const int ck = t + j * 256;
    const int kr = ck >> 4, ks = ck & 15;
    *(bf16x8*)((char*)Ks + kr * 256 + ((ks ^ (kr & 7)) * 16)) = stK[j];
    const int vd = ck >> 3, vs = ck & 7;
    *(bf16x8*)((char*)Vs + vd * 128 + ((vs ^ (vd & 7)) * 16)) = stV[j];
  }
  __syncthreads();

  for (int tile = 0; tile < NT; ++tile) {
    const int kb = tile * KVB;
    // ---- S-phase: S^T = K . Q^T  (K-frag shared across both q-sets) ----
    f32x4 sacc[2][4] = {};
#pragma unroll
    for (int kbi = 0; kbi < 4; ++kbi) {
      const int krow = kbi * 16 + lq;
#pragma unroll
      for (int c = 0; c < 4; ++c) {
        const bf16x8 kf = *(const bf16x8*)((char*)Ks + krow * 256 + (((c * 4 + lg) ^ (krow & 7)) * 16));
        sacc[0][kbi] = __builtin_amdgcn_mfma_f32_16x16x32_bf16(kf, qf[0][c], sacc[0][kbi], 0, 0, 0);
        sacc[1][kbi] = __builtin_amdgcn_mfma_f32_16x16x32_bf16(kf, qf[1][c], sacc[1][kbi], 0, 0, 0);
      }
    }
    // ---- issue next-tile global loads (latency hides under softmax+PV) ----
    const int kbn = min(kb + KVB, (NT - 1) * KVB);
#pragma unroll
    for (int j = 0; j < 4; ++j) {
      const int ck = t + j * 256;
      const int kr = ck >> 4, ks = ck & 15;
      stK[j] = *(const bf16x8*)(kh + (size_t)min(kbn + kr, SEQ - 1) * DIM + ks * 8);
      const int vd = ck >> 3, vs = ck & 7;
      stV[j] = *(const bf16x8*)(vh + (size_t)vd * SEQP + kbn + vs * 8);
    }
    // ---- softmax (online) per q-set ----
    float alpha[2];
#pragma unroll
    for (int qs = 0; qs < 2; ++qs) {
      float s[16];
      float mt = -1e30f;
#pragma unroll
      for (int kbi = 0; kbi < 4; ++kbi)
#pragma unroll
        for (int r = 0; r < 4; ++r) {
          const int key = kb + kbi * 16 + lg * 4 + r;
          float v = sacc[qs][kbi][r];
          if (key >= SEQ) v = -1e30f;
          s[kbi * 4 + r] = v;
          mt = fmaxf(mt, v);
        }
      mt = fmaxf(mt, __shfl_xor(mt, 16));
      mt = fmaxf(mt, __shfl_xor(mt, 32));
      const float m_new = fmaxf(m_run[qs], mt);
      const float al = __expf(m_run[qs] - m_new);
      // fused attn-map over keys < XS (raw scores, own online chain)
      if (kb < XS) {
        float lm = -1e30f;
#pragma unroll
        for (int i = 0; i < 16; ++i) {
          const int key = kb + (i >> 2) * 16 + lg * 4 + (i & 3);
          if (key < XS) lm = fmaxf(lm, s[i]);
        }
        const float m2n  = fmaxf(m2[qs], lm);
        const float beta = __expf(m2[qs] - m2n);
        d2[qs] *= beta; n0[qs] *= beta; n1[qs] *= beta;
        m2[qs] = m2n;
#pragma unroll
        for (int i = 0; i < 16; ++i) {
          const int key = kb + (i >> 2) * 16 + lg * 4 + (i & 3);
          if (key < XS) {
            const float pe = __expf(s[i] - m2n);
            d2[qs] += pe;
            n0[qs] = fmaf(pe, mask[key], n0[qs]);
            n1[qs] = fmaf(pe, mask[XS + key], n1[qs]);
          }
        }
      }
      float ps = 0.f;
#pragma unroll
      for (int i = 0; i < 16; ++i) { s[i] = __expf(s[i] - m_new); ps += s[i]; }
      ps += __shfl_xor(ps, 16);
      ps += __shfl_xor(ps, 32);
      l_run[qs] = l_run[qs] * al + ps;
      m_run[qs] = m_new;
      alpha[qs] = al;
      // write P tile (wave-private)
#pragma unroll
      for (int kbi = 0; kbi < 4; ++kbi) {
        bf16x4 pb;
#pragma unroll
        for (int r = 0; r < 4; ++r) pb[r] = (short)f2bf(s[kbi * 4 + r]);
        *(bf16x4*)&P[qs * 16 + lq][kbi * 16 + lg * 4] = pb;
      }
    }
    // ---- rescale O accumulators ----
#pragma unroll
    for (int qs = 0; qs < 2; ++qs)
#pragma unroll
      for (int db = 0; db < 8; ++db) {
        acc[qs][db][0] *= alpha[qs]; acc[qs][db][1] *= alpha[qs];
        acc[qs][db][2] *= alpha[qs]; acc[qs][db][3] *= alpha[qs];
      }
    // ---- PV: acc[d][q] += V^T . P  (V-frag shared across q-sets) ----
#pragma unroll
    for (int kk = 0; kk < 2; ++kk) {
      const bf16x8 pf0 = *(const bf16x8*)&P[lq][kk * 32 + lg * 8];
      const bf16x8 pf1 = *(const bf16x8*)&P[16 + lq][kk * 32 + lg * 8];
#pragma unroll
      for (int db = 0; db < 8; ++db) {
        const int vd = db * 16 + lq;
        const bf16x8 vf = *(const bf16x8*)((char*)Vs + vd * 128 + (((kk * 4 + lg) ^ (vd & 7)) * 16));
        acc[0][db] = __builtin_amdgcn_mfma_f32_16x16x32_bf16(vf, pf0, acc[0][db], 0, 0, 0);
        acc[1][db] = __builtin_amdgcn_mfma_f32_16x16x32_bf16(vf, pf1, acc[1][db], 0, 0, 0);
      }
    }
    __syncthreads();
    // ---- write staged tile t+1 into LDS (swizzled) ----
#pragma unroll
    for (int j = 0; j < 4; ++j) {
      const int ck = t + j * 256;
      const int kr = ck >> 4, ks = ck & 15;
      *(bf16x8*)((char*)Ks + kr * 256 + ((ks ^ (kr & 7)) * 16)) = stK[j];
      const int vd = ck >> 3, vs = ck & 7;
      *(bf16x8*)((char*)Vs + vd * 128 + ((vs ^ (vd & 7)) * 16)) = stV[j];
    }
    __syncthreads();
  }

  // ---- epilogue: O write ----
#pragma unroll
  for (int qs = 0; qs < 2; ++qs) {
    const int qrow = qbase + qs * 16 + lq;
    if (qrow < SEQ) {
      const float inv = 1.f / l_run[qs];
#pragma unroll
      for (int db = 0; db < 8; ++db) {
        bf16x4 o;
#pragma unroll
        for (int r = 0; r < 4; ++r) o[r] = (short)f2bf(acc[qs][db][r] * inv);
        *(bf16x4*)(ob + (size_t)qrow * DIM + h * HD + db * 16 + lg * 4) = o;
      }
    }
  }
  // ---- attn-map: merge lane-groups, one atomic per (head,row) ----
#pragma unroll
  for (int qs = 0; qs < 2; ++qs) {
    float mm2 = m2[qs], dd2 = d2[qs], nn0 = n0[qs], nn1 = n1[qs];
#pragma unroll
    for (int off = 16; off <= 32; off <<= 1) {
      const float om = __shfl_xor(mm2, off);
      const float od = __shfl_xor(dd2, off);
      const float o0 = __shfl_xor(nn0, off);
      const float o1 = __shfl_xor(nn1, off);
      const float mm = fmaxf(mm2, om);
      const float sa = __expf(mm2 - mm);
      const float sb = __expf(om - mm);
      dd2 = dd2 * sa + od * sb;
      nn0 = nn0 * sa + o0 * sb;
      nn1 = nn1 * sa + o1 * sb;
      mm2 = mm;
    }
    const int qrow = qbase + qs * 16 + lq;
    if (lane < 16 && qrow < SEQ) {
      const float invd = 1.f / (dd2 * (float)HEADS);
      atomicAdd(&amap[qrow],       nn0 * invd / cnt[0]);
      atomicAdd(&amap[SEQ + qrow], nn1 * invd / cnt[1]);
    }
  }
}

// ============================================================
extern "C" void kernel_launch(void* const* d_in, const int* in_sizes, int n_in,
                              void* d_out, int out_size, void* d_ws, size_t ws_size,
                              hipStream_t stream) {
  const float* x    = (const float*)d_in[0];
  const float* Wq   = (const float*)d_in[1];
  const float* bq   = (const float*)d_in[2];
  const float* Wk   = (const float*)d_in[3];
  const float* bk   = (const float*)d_in[4];
  const float* Wv   = (const float*)d_in[5];
  const float* bv   = (const float*)d_in[6];
  const float* Wo   = (const float*)d_in[7];
  const float* bo   = (const float*)d_in[8];
  const float* gq   = (const float*)d_in[9];
  const float* gk   = (const float*)d_in[10];
  const float* fc   = (const float*)d_in[11];
  const float* fs   = (const float*)d_in[12];
  const float* mask = (const float*)d_in[13];

  float* out  = (float*)d_out;
  float* amap = out + SD;

  float* f32tmp      = (float*)d_ws;                    // SD f32
  unsigned short* xb = (unsigned short*)(f32tmp + SD);  // SD bf16
  unsigned short* qb = xb + SD;
  unsigned short* kb = qb + SD;
  unsigned short* vt = kb + SD;                         // DIM*SEQP bf16
  unsigned short* ob = vt + (size_t)DIM * SEQP;
  unsigned short* wb = ob + SD;                         // DIM*DIM bf16
  float* cnt = (float*)(wb + (size_t)DIM * DIM);

  prep_kernel<<<1, 256, 0, stream>>>(mask, amap, cnt);
  padzero<<<64, 256, 0, stream>>>(vt);
  to_bf16<<<2048, 256, 0, stream>>>(x, xb, (int)(SD / 4));

  const dim3 gg((SEQ + 127) / 128, DIM / 128);
  constexpr int W4 = DIM * DIM / 4;

  // V projection -> V^T bf16
  to_bf16<<<1024, 256, 0, stream>>>(Wv, wb, W4);
  gemm_mfma<2><<<gg, 256, 0, stream>>>(xb, wb, bv, vt, SEQ);

  const float scale = 0.08838834764831845f;  // 1/sqrt(128)
  to_bf16<<<1024, 256, 0, stream>>>(Wq, wb, W4);
  gemm_mfma<0><<<gg, 256, 0, stream>>>(xb, wb, bq, f32tmp, SEQ);
  rms_rope_b<<<SEQ, 256, 0, stream>>>(f32tmp, gq, fc, fs, scale, qb);
  to_bf16<<<1024, 256, 0, stream>>>(Wk, wb, W4);
  gemm_mfma<0><<<gg, 256, 0, stream>>>(xb, wb, bk, f32tmp, SEQ);
  rms_rope_b<<<SEQ, 256, 0, stream>>>(f32tmp, gk, fc, fs, 1.0f, kb);

  // attention + attn-map
  const dim3 fg((SEQ + 127) / 128, HEADS);
  flash_mfma<<<fg, 256, 0, stream>>>(qb, kb, vt, mask, cnt, ob, amap);

  // output projection (f32 out)
  to_bf16<<<1024, 256, 0, stream>>>(Wo, wb, W4);
  gemm_mfma<0><<<gg, 256, 0, stream>>>(ob, wb, bo, out, SEQ);
}

// Round 4
// 468.185 us; speedup vs baseline: 22.6833x; 1.2157x over previous
//
#include <hip/hip_runtime.h>
#include <hip/hip_bf16.h>
#include <math.h>

// ---- problem constants ----
constexpr int SEQ   = 4356;
constexpr int DIM   = 1536;
constexpr int HEADS = 12;
constexpr int HD    = 128;
constexpr int CH    = 64;           // HD/2 rope channels
constexpr int C0c   = 22;
constexpr int C1c   = 21;
constexpr int WWc   = 22;
constexpr int HHWW  = 484;
constexpr int XS    = 484;
constexpr int KVB   = 64;
constexpr int NT    = (SEQ + KVB - 1) / KVB;   // 69 tiles
constexpr int SEQP  = NT * KVB;                // 4416 padded V^T pitch
constexpr size_t SD = (size_t)SEQ * DIM;

typedef float f32x4 __attribute__((ext_vector_type(4)));
typedef short bf16x8 __attribute__((ext_vector_type(8)));
typedef short bf16x4 __attribute__((ext_vector_type(4)));

__device__ inline unsigned short f2bf(float f) {
  union { float f; unsigned u; } x; x.f = f;
  return (unsigned short)((x.u + 0x7FFFu + ((x.u >> 16) & 1u)) >> 16);
}

#define GLD16(g, l)                                                                        \
  __builtin_amdgcn_global_load_lds((const __attribute__((address_space(1))) unsigned*)    \
                                       (const void*)(g),                                  \
                                   (__attribute__((address_space(3))) unsigned*)(void*)(l),\
                                   16, 0, 0)

// ============================================================
// prep: zero attn-map, mask counts, build padded float4 mask table
// msk4[i] = {mask0[i], mask1[i], i<XS, 0} for i<512
// ============================================================
__global__ __launch_bounds__(256) void prep_kernel(const float* __restrict__ mask,
                                                   float* __restrict__ amap,
                                                   float* __restrict__ cnt,
                                                   float4* __restrict__ msk4) {
  int t = threadIdx.x;
  for (int i = t; i < 2 * SEQ; i += 256) amap[i] = 0.f;
  for (int i = t; i < 512; i += 256) {
    float4 v;
    v.x = (i < XS) ? mask[i] : 0.f;
    v.y = (i < XS) ? mask[XS + i] : 0.f;
    v.z = (i < XS) ? 1.f : 0.f;
    v.w = 0.f;
    msk4[i] = v;
  }
  float c0 = 0.f, c1 = 0.f;
  for (int i = t; i < XS; i += 256) { c0 += mask[i]; c1 += mask[XS + i]; }
  __shared__ float red0[256];
  __shared__ float red1[256];
  red0[t] = c0; red1[t] = c1;
  __syncthreads();
  for (int off = 128; off > 0; off >>= 1) {
    if (t < off) { red0[t] += red0[t + off]; red1[t] += red1[t + off]; }
    __syncthreads();
  }
  if (t == 0) { cnt[0] = red0[0]; cnt[1] = red1[0]; }
}

// zero V^T tail columns (keys SEQ..SEQP)
__global__ __launch_bounds__(256) void padzero(unsigned short* __restrict__ vt) {
  const int pad = SEQP - SEQ;
  const int total = DIM * pad;
  for (int i = blockIdx.x * 256 + threadIdx.x; i < total; i += gridDim.x * 256) {
    const int d = i / pad, c = i - d * pad;
    vt[(size_t)d * SEQP + SEQ + c] = 0;
  }
}

// f32 -> bf16 (RNE), vectorized
__global__ __launch_bounds__(256) void to_bf16(const float* __restrict__ in,
                                               unsigned short* __restrict__ out, int n4) {
  for (int i = blockIdx.x * 256 + threadIdx.x; i < n4; i += gridDim.x * 256) {
    const float4 v = ((const float4*)in)[i];
    ushort4 o;
    o.x = f2bf(v.x); o.y = f2bf(v.y); o.z = f2bf(v.z); o.w = f2bf(v.w);
    ((ushort4*)out)[i] = o;
  }
}

// 4 weight matrices in one launch (z selects)
__global__ __launch_bounds__(256) void to_bf16_w(const float* __restrict__ W0, const float* __restrict__ W1,
                                                 const float* __restrict__ W2, const float* __restrict__ W3,
                                                 unsigned short* __restrict__ o0, unsigned short* __restrict__ o1,
                                                 unsigned short* __restrict__ o2, unsigned short* __restrict__ o3,
                                                 int n4) {
  const int z = blockIdx.z;
  const float* in = (z == 0) ? W0 : (z == 1) ? W1 : (z == 2) ? W2 : W3;
  unsigned short* out = (z == 0) ? o0 : (z == 1) ? o1 : (z == 2) ? o2 : o3;
  for (int i = blockIdx.x * 256 + threadIdx.x; i < n4; i += gridDim.x * 256) {
    const float4 v = ((const float4*)in)[i];
    ushort4 o;
    o.x = f2bf(v.x); o.y = f2bf(v.y); o.z = f2bf(v.z); o.w = f2bf(v.w);
    ((ushort4*)out)[i] = o;
  }
}

// ============================================================
// combined QKV MFMA GEMM (NT): z=0 -> Q f32, z=1 -> K f32, z=2 -> V^T bf16
// ============================================================
__global__ __launch_bounds__(256) void gemm_qkv(const unsigned short* __restrict__ A,
                                                const unsigned short* __restrict__ B0,
                                                const unsigned short* __restrict__ B1,
                                                const unsigned short* __restrict__ B2,
                                                const float* __restrict__ bq,
                                                const float* __restrict__ bk,
                                                const float* __restrict__ bv,
                                                float* __restrict__ o0,
                                                float* __restrict__ o1,
                                                unsigned short* __restrict__ vtout,
                                                int M) {
  __shared__ unsigned short As[128 * 64];
  __shared__ unsigned short Bs[128 * 64];
  const int z = blockIdx.z;
  const unsigned short* B = (z == 0) ? B0 : (z == 1) ? B1 : B2;
  const float* bias = (z == 0) ? bq : (z == 1) ? bk : bv;
  const int t    = threadIdx.x;
  const int lane = t & 63;
  const int w    = t >> 6;
  const int wr   = w >> 1, wc = w & 1;
  const int bm = blockIdx.x * 128, bn = blockIdx.y * 128;
  const int lq = lane & 15, lg = lane >> 4;
  f32x4 acc[4][4] = {};
  for (int k0 = 0; k0 < DIM; k0 += 64) {
#pragma unroll
    for (int i = 0; i < 4; ++i) {
      const int idx = i * 256 + t;
      const int row = idx >> 3;
      const int c8  = (idx & 7) * 8;
      const int ga  = min(bm + row, M - 1);
      GLD16(A + (size_t)ga * DIM + k0 + c8, As + idx * 8);
      const int gb  = bn + row;
      GLD16(B + (size_t)gb * DIM + k0 + c8, Bs + idx * 8);
    }
    __syncthreads();
#pragma unroll
    for (int kk = 0; kk < 2; ++kk) {
      bf16x8 af[4], bf[4];
#pragma unroll
      for (int m = 0; m < 4; ++m)
        af[m] = *(const bf16x8*)(As + (wr * 64 + m * 16 + lq) * 64 + kk * 32 + lg * 8);
#pragma unroll
      for (int n = 0; n < 4; ++n)
        bf[n] = *(const bf16x8*)(Bs + (wc * 64 + n * 16 + lq) * 64 + kk * 32 + lg * 8);
#pragma unroll
      for (int m = 0; m < 4; ++m)
#pragma unroll
        for (int n = 0; n < 4; ++n)
          acc[m][n] = __builtin_amdgcn_mfma_f32_16x16x32_bf16(af[m], bf[n], acc[m][n], 0, 0, 0);
    }
    __syncthreads();
  }
#pragma unroll
  for (int n = 0; n < 4; ++n) {
    const int col = bn + wc * 64 + n * 16 + lq;
    const float bv2 = bias[col];
#pragma unroll
    for (int m = 0; m < 4; ++m) {
      const int rm = bm + wr * 64 + m * 16 + lg * 4;
      if (z < 2) {
        float* C = (z == 0) ? o0 : o1;
#pragma unroll
        for (int r = 0; r < 4; ++r) {
          const int row = rm + r;
          if (row < M) C[(size_t)row * DIM + col] = acc[m][n][r] + bv2;
        }
      } else {
        if (rm < M) {
          bf16x4 o;
#pragma unroll
          for (int r = 0; r < 4; ++r) o[r] = (short)f2bf(acc[m][n][r] + bv2);
          *(bf16x4*)(vtout + (size_t)col * SEQP + rm) = o;
        }
      }
    }
  }
}

// ============================================================
// single-output GEMM for the final projection (f32 out)
// ============================================================
__global__ __launch_bounds__(256) void gemm_mfma(const unsigned short* __restrict__ A,
                                                 const unsigned short* __restrict__ B,
                                                 const float* __restrict__ bias,
                                                 float* __restrict__ C, int M) {
  __shared__ unsigned short As[128 * 64];
  __shared__ unsigned short Bs[128 * 64];
  const int t    = threadIdx.x;
  const int lane = t & 63;
  const int w    = t >> 6;
  const int wr   = w >> 1, wc = w & 1;
  const int bm = blockIdx.x * 128, bn = blockIdx.y * 128;
  const int lq = lane & 15, lg = lane >> 4;
  f32x4 acc[4][4] = {};
  for (int k0 = 0; k0 < DIM; k0 += 64) {
#pragma unroll
    for (int i = 0; i < 4; ++i) {
      const int idx = i * 256 + t;
      const int row = idx >> 3;
      const int c8  = (idx & 7) * 8;
      const int ga  = min(bm + row, M - 1);
      GLD16(A + (size_t)ga * DIM + k0 + c8, As + idx * 8);
      const int gb  = bn + row;
      GLD16(B + (size_t)gb * DIM + k0 + c8, Bs + idx * 8);
    }
    __syncthreads();
#pragma unroll
    for (int kk = 0; kk < 2; ++kk) {
      bf16x8 af[4], bf[4];
#pragma unroll
      for (int m = 0; m < 4; ++m)
        af[m] = *(const bf16x8*)(As + (wr * 64 + m * 16 + lq) * 64 + kk * 32 + lg * 8);
#pragma unroll
      for (int n = 0; n < 4; ++n)
        bf[n] = *(const bf16x8*)(Bs + (wc * 64 + n * 16 + lq) * 64 + kk * 32 + lg * 8);
#pragma unroll
      for (int m = 0; m < 4; ++m)
#pragma unroll
        for (int n = 0; n < 4; ++n)
          acc[m][n] = __builtin_amdgcn_mfma_f32_16x16x32_bf16(af[m], bf[n], acc[m][n], 0, 0, 0);
    }
    __syncthreads();
  }
#pragma unroll
  for (int n = 0; n < 4; ++n) {
    const int col = bn + wc * 64 + n * 16 + lq;
    const float bv = bias[col];
#pragma unroll
    for (int m = 0; m < 4; ++m) {
      const int rm = bm + wr * 64 + m * 16 + lg * 4;
#pragma unroll
      for (int r = 0; r < 4; ++r) {
        const int row = rm + r;
        if (row < M) C[(size_t)row * DIM + col] = acc[m][n][r] + bv;
      }
    }
  }
}

// ============================================================
// RMSNorm + RoPE, f32 in -> bf16 out (scale folded into output)
// ============================================================
__global__ __launch_bounds__(256) void rms_rope_b(const float* __restrict__ y,
                                                  const float* __restrict__ g,
                                                  const float* __restrict__ fcos,
                                                  const float* __restrict__ fsin,
                                                  float scale,
                                                  unsigned short* __restrict__ outb) {
  const int s = blockIdx.x;
  const float* row = y + (size_t)s * DIM;
  const int t = threadIdx.x;
  float ss = 0.f;
  for (int i = t; i < DIM / 4; i += 256) {
    const float4 v = ((const float4*)row)[i];
    ss += v.x * v.x + v.y * v.y + v.z * v.z + v.w * v.w;
  }
#pragma unroll
  for (int off = 1; off < 64; off <<= 1) ss += __shfl_xor(ss, off);
  __shared__ float wred[4];
  if ((t & 63) == 0) wred[t >> 6] = ss;
  __syncthreads();
  const float tot = wred[0] + wred[1] + wred[2] + wred[3];
  const float rs = rsqrtf(tot * (1.0f / DIM) + 1e-6f);
  const int fi  = s / HHWW;
  const int rem = s - fi * HHWW;
  const int hi  = rem / WWc;
  const int wi  = rem - hi * WWc;
  for (int p = t; p < DIM / 2; p += 256) {
    const int head = p >> 6;
    const int c    = p & 63;
    const int idx  = head * HD + 2 * c;
    const int trow = (c < C0c) ? fi : ((c < C0c + C1c) ? hi : wi);
    const float co = fcos[trow * CH + c];
    const float si = fsin[trow * CH + c];
    const float a  = row[idx] * rs * g[idx];
    const float b  = row[idx + 1] * rs * g[idx + 1];
    ushort2 pr;
    pr.x = f2bf((a * co - b * si) * scale);
    pr.y = f2bf((a * si + b * co) * scale);
    *(ushort2*)(outb + (size_t)s * DIM + idx) = pr;
  }
}

// ============================================================
// Flash attention v3: 64 q/block (4 waves x 16 q), KVB=64 LDS tiles,
// reg-prefetch, defer-max (THR=8), map reuses main-frame p, cvt_pk P.
// ============================================================
#define TILE_BODY(KB_, MAP_, LAST_, PRE_)                                               \
  {                                                                                     \
    const int kb_ = (KB_);                                                              \
    f32x4 sacc[4] = {};                                                                 \
    _Pragma("unroll")                                                                   \
    for (int kbi = 0; kbi < 4; ++kbi) {                                                 \
      const int krow = kbi * 16 + lq;                                                   \
      _Pragma("unroll")                                                                 \
      for (int c = 0; c < 4; ++c) {                                                     \
        const bf16x8 kf = *(const bf16x8*)((char*)Ks + krow * 256 +                     \
                            (((c * 4 + lg) ^ (krow & 7)) * 16));                        \
        sacc[kbi] = __builtin_amdgcn_mfma_f32_16x16x32_bf16(kf, qf[c], sacc[kbi], 0, 0, 0); \
      }                                                                                 \
    }                                                                                   \
    if (PRE_) {                                                                         \
      const int kbn = kb_ + KVB;                                                        \
      _Pragma("unroll")                                                                 \
      for (int j = 0; j < 4; ++j) {                                                     \
        const int ck = t + j * 256;                                                     \
        const int kr = ck >> 4, ks2 = ck & 15;                                          \
        stK[j] = *(const bf16x8*)(kh + (size_t)min(kbn + kr, SEQ - 1) * DIM + ks2 * 8); \
        const int vd = ck >> 3, vs2 = ck & 7;                                           \
        stV[j] = *(const bf16x8*)(vh + (size_t)vd * SEQP + kbn + vs2 * 8);              \
      }                                                                                 \
    }                                                                                   \
    float sv[16];                                                                       \
    float mt = -1e30f;                                                                  \
    _Pragma("unroll")                                                                   \
    for (int i = 0; i < 16; ++i) {                                                      \
      float v = sacc[i >> 2][i & 3];                                                    \
      if (LAST_) {                                                                      \
        const int key = kb_ + (i >> 2) * 16 + lg * 4 + (i & 3);                         \
        if (key >= SEQ) v = -1e30f;                                                     \
      }                                                                                 \
      sv[i] = v;                                                                        \
      mt = fmaxf(mt, v);                                                                \
    }                                                                                   \
    mt = fmaxf(mt, __shfl_xor(mt, 16));                                                 \
    mt = fmaxf(mt, __shfl_xor(mt, 32));                                                 \
    const bool need = __any(mt > m_run + 8.f);                                          \
    if (need) {                                                                         \
      const float m_new = fmaxf(m_run, mt);                                             \
      const float alpha = __expf(m_run - m_new);                                        \
      m_run = m_new;                                                                    \
      l_run *= alpha;                                                                   \
      _Pragma("unroll")                                                                 \
      for (int db = 0; db < 8; ++db) {                                                  \
        acc[db][0] *= alpha; acc[db][1] *= alpha;                                       \
        acc[db][2] *= alpha; acc[db][3] *= alpha;                                       \
      }                                                                                 \
      if (MAP_) { d2 *= alpha; n0 *= alpha; n1 *= alpha; }                              \
    }                                                                                   \
    float ps = 0.f;                                                                     \
    _Pragma("unroll")                                                                   \
    for (int i = 0; i < 16; ++i) { sv[i] = __expf(sv[i] - m_run); ps += sv[i]; }        \
    ps += __shfl_xor(ps, 16);                                                           \
    ps += __shfl_xor(ps, 32);                                                           \
    l_run += ps;                                                                        \
    if (MAP_) {                                                                         \
      _Pragma("unroll")                                                                 \
      for (int i = 0; i < 16; ++i) {                                                    \
        const int key = kb_ + (i >> 2) * 16 + lg * 4 + (i & 3);                         \
        const float4 mv = Msk[key];                                                     \
        n0 = fmaf(sv[i], mv.x, n0);                                                     \
        n1 = fmaf(sv[i], mv.y, n1);                                                     \
        d2 = fmaf(sv[i], mv.z, d2);                                                     \
      }                                                                                 \
    }                                                                                   \
    _Pragma("unroll")                                                                   \
    for (int kbi = 0; kbi < 4; ++kbi) {                                                 \
      unsigned r0, r1;                                                                  \
      asm("v_cvt_pk_bf16_f32 %0, %1, %2" : "=v"(r0) : "v"(sv[kbi * 4 + 0]), "v"(sv[kbi * 4 + 1])); \
      asm("v_cvt_pk_bf16_f32 %0, %1, %2" : "=v"(r1) : "v"(sv[kbi * 4 + 2]), "v"(sv[kbi * 4 + 3])); \
      uint2 pw; pw.x = r0; pw.y = r1;                                                   \
      *(uint2*)&P[lq][kbi * 16 + lg * 4] = pw;                                          \
    }                                                                                   \
    _Pragma("unroll")                                                                   \
    for (int kk = 0; kk < 2; ++kk) {                                                    \
      const bf16x8 pf = *(const bf16x8*)&P[lq][kk * 32 + lg * 8];                       \
      _Pragma("unroll")                                                                 \
      for (int db = 0; db < 8; ++db) {                                                  \
        const int vd = db * 16 + lq;                                                    \
        const bf16x8 vf = *(const bf16x8*)((char*)Vs + vd * 128 +                       \
                            (((kk * 4 + lg) ^ (vd & 7)) * 16));                         \
        acc[db] = __builtin_amdgcn_mfma_f32_16x16x32_bf16(vf, pf, acc[db], 0, 0, 0);    \
      }                                                                                 \
    }                                                                                   \
    if (PRE_) {                                                                         \
      __syncthreads();                                                                  \
      _Pragma("unroll")                                                                 \
      for (int j = 0; j < 4; ++j) {                                                     \
        const int ck = t + j * 256;                                                     \
        const int kr = ck >> 4, ks2 = ck & 15;                                          \
        *(bf16x8*)((char*)Ks + kr * 256 + ((ks2 ^ (kr & 7)) * 16)) = stK[j];            \
        const int vd = ck >> 3, vs2 = ck & 7;                                           \
        *(bf16x8*)((char*)Vs + vd * 128 + ((vs2 ^ (vd & 7)) * 16)) = stV[j];            \
      }                                                                                 \
      __syncthreads();                                                                  \
    }                                                                                   \
  }

__global__ __launch_bounds__(256) void flash_mfma(const unsigned short* __restrict__ qbuf,
                                                  const unsigned short* __restrict__ kbuf,
                                                  const unsigned short* __restrict__ vt,
                                                  const float4* __restrict__ msk4,
                                                  const float* __restrict__ cnt,
                                                  unsigned short* __restrict__ ob,
                                                  float* __restrict__ amap) {
  const int h    = blockIdx.y;
  const int t    = threadIdx.x;
  const int w    = t >> 6;
  const int lane = t & 63;
  const int lq   = lane & 15, lg = lane >> 4;
  const int qbase = blockIdx.x * 64 + w * 16;

  __shared__ __align__(16) unsigned short Ks[64 * 128];
  __shared__ __align__(16) unsigned short Vs[128 * 64];
  __shared__ __align__(16) unsigned short Plds[4][16][72];
  __shared__ float4 Msk[512];
  unsigned short (*P)[72] = Plds[w];

  const unsigned short* kh = kbuf + h * HD;
  const unsigned short* vh = vt + (size_t)(h * HD) * SEQP;

  for (int i = t; i < 512; i += 256) Msk[i] = msk4[i];

  const int qsrc = min(qbase + lq, SEQ - 1);
  bf16x8 qf[4];
#pragma unroll
  for (int c = 0; c < 4; ++c)
    qf[c] = *(const bf16x8*)(qbuf + (size_t)qsrc * DIM + h * HD + c * 32 + lg * 8);

  f32x4 acc[8] = {};
  float m_run = -1e30f, l_run = 0.f;
  float d2 = 0.f, n0 = 0.f, n1 = 0.f;

  bf16x8 stK[4], stV[4];
  // prologue: stage tile 0
#pragma unroll
  for (int j = 0; j < 4; ++j) {
    const int ck = t + j * 256;
    const int kr = ck >> 4, ks2 = ck & 15;
    stK[j] = *(const bf16x8*)(kh + (size_t)min(kr, SEQ - 1) * DIM + ks2 * 8);
    const int vd = ck >> 3, vs2 = ck & 7;
    stV[j] = *(const bf16x8*)(vh + (size_t)vd * SEQP + vs2 * 8);
  }
#pragma unroll
  for (int j = 0; j < 4; ++j) {
    const int ck = t + j * 256;
    const int kr = ck >> 4, ks2 = ck & 15;
    *(bf16x8*)((char*)Ks + kr * 256 + ((ks2 ^ (kr & 7)) * 16)) = stK[j];
    const int vd = ck >> 3, vs2 = ck & 7;
    *(bf16x8*)((char*)Vs + vd * 128 + ((vs2 ^ (vd & 7)) * 16)) = stV[j];
  }
  __syncthreads();

  for (int tile = 0; tile < 8; ++tile)          TILE_BODY(tile * KVB, true,  false, true);
  for (int tile = 8; tile < NT - 1; ++tile)     TILE_BODY(tile * KVB, false, false, true);
  TILE_BODY((NT - 1) * KVB, false, true, false);

  // epilogue: O write
  const int qrow = qbase + lq;
  if (qrow < SEQ) {
    const float inv = 1.f / l_run;
#pragma unroll
    for (int db = 0; db < 8; ++db) {
      bf16x4 o;
#pragma unroll
      for (int r = 0; r < 4; ++r) o[r] = (short)f2bf(acc[db][r] * inv);
      *(bf16x4*)(ob + (size_t)qrow * DIM + h * HD + db * 16 + lg * 4) = o;
    }
  }
  // attn-map: lane groups share the same frame -> plain sums
  d2 += __shfl_xor(d2, 16); d2 += __shfl_xor(d2, 32);
  n0 += __shfl_xor(n0, 16); n0 += __shfl_xor(n0, 32);
  n1 += __shfl_xor(n1, 16); n1 += __shfl_xor(n1, 32);
  if (lane < 16 && qrow < SEQ) {
    const float invd = 1.f / (d2 * (float)HEADS);
    atomicAdd(&amap[qrow],       n0 * invd / cnt[0]);
    atomicAdd(&amap[SEQ + qrow], n1 * invd / cnt[1]);
  }
}

// ============================================================
extern "C" void kernel_launch(void* const* d_in, const int* in_sizes, int n_in,
                              void* d_out, int out_size, void* d_ws, size_t ws_size,
                              hipStream_t stream) {
  const float* x    = (const float*)d_in[0];
  const float* Wq   = (const float*)d_in[1];
  const float* bq   = (const float*)d_in[2];
  const float* Wk   = (const float*)d_in[3];
  const float* bk   = (const float*)d_in[4];
  const float* Wv   = (const float*)d_in[5];
  const float* bv   = (const float*)d_in[6];
  const float* Wo   = (const float*)d_in[7];
  const float* bo   = (const float*)d_in[8];
  const float* gq   = (const float*)d_in[9];
  const float* gk   = (const float*)d_in[10];
  const float* fc   = (const float*)d_in[11];
  const float* fs   = (const float*)d_in[12];
  const float* mask = (const float*)d_in[13];

  float* out  = (float*)d_out;
  float* amap = out + SD;
  float* f32a = out;                                    // Q f32 scratch in d_out

  float* f32b        = (float*)d_ws;                    // SD f32 (K); later ob
  unsigned short* xb = (unsigned short*)(f32b + SD);    // SD bf16
  unsigned short* qb = xb + SD;
  unsigned short* kb = qb + SD;
  unsigned short* vt = kb + SD;                         // DIM*SEQP bf16
  unsigned short* wqb = vt + (size_t)DIM * SEQP;        // 4x DIM*DIM bf16
  unsigned short* wkb = wqb + (size_t)DIM * DIM;
  unsigned short* wvb = wkb + (size_t)DIM * DIM;
  unsigned short* wob = wvb + (size_t)DIM * DIM;
  float4* msk4 = (float4*)(wob + (size_t)DIM * DIM);    // 512
  float* cnt  = (float*)(msk4 + 512);
  unsigned short* ob = (unsigned short*)f32b;           // alias: f32b dead by then

  prep_kernel<<<1, 256, 0, stream>>>(mask, amap, cnt, msk4);
  padzero<<<64, 256, 0, stream>>>(vt);
  to_bf16<<<2048, 256, 0, stream>>>(x, xb, (int)(SD / 4));
  constexpr int W4 = DIM * DIM / 4;
  to_bf16_w<<<dim3(512, 1, 4), 256, 0, stream>>>(Wq, Wk, Wv, Wo, wqb, wkb, wvb, wob, W4);

  const dim3 gg((SEQ + 127) / 128, DIM / 128, 3);
  gemm_qkv<<<gg, 256, 0, stream>>>(xb, wqb, wkb, wvb, bq, bk, bv, f32a, f32b, vt, SEQ);

  const float scale = 0.08838834764831845f;  // 1/sqrt(128)
  rms_rope_b<<<SEQ, 256, 0, stream>>>(f32a, gq, fc, fs, scale, qb);
  rms_rope_b<<<SEQ, 256, 0, stream>>>(f32b, gk, fc, fs, 1.0f, kb);

  const dim3 fg((SEQ + 63) / 64, HEADS);
  flash_mfma<<<fg, 256, 0, stream>>>(qb, kb, vt, msk4, cnt, ob, amap);

  const dim3 go((SEQ + 127) / 128, DIM / 128);
  gemm_mfma<<<go, 256, 0, stream>>>(ob, wob, bo, out, SEQ);
}

// Round 5
// 467.180 us; speedup vs baseline: 22.7321x; 1.0022x over previous
//
#include <hip/hip_runtime.h>
#include <hip/hip_bf16.h>
#include <math.h>

// ---- problem constants ----
constexpr int SEQ   = 4356;
constexpr int DIM   = 1536;
constexpr int HEADS = 12;
constexpr int HD    = 128;
constexpr int CH    = 64;           // HD/2 rope channels
constexpr int C0c   = 22;
constexpr int C1c   = 21;
constexpr int WWc   = 22;
constexpr int HHWW  = 484;
constexpr int XS    = 484;
constexpr int KVB   = 32;
constexpr int NT    = (SEQ + KVB - 1) / KVB;   // 137 tiles
constexpr int SEQP  = 4416;                    // padded V^T row pitch
constexpr int VP    = 40;                      // Vs LDS pitch in shorts (80B, 16B-aligned)
constexpr size_t SD = (size_t)SEQ * DIM;

typedef float f32x4 __attribute__((ext_vector_type(4)));
typedef short bf16x8 __attribute__((ext_vector_type(8)));
typedef short bf16x4 __attribute__((ext_vector_type(4)));

__device__ inline unsigned short f2bf(float f) {
  union { float f; unsigned u; } x; x.f = f;
  return (unsigned short)((x.u + 0x7FFFu + ((x.u >> 16) & 1u)) >> 16);
}

#define GLD16(g, l)                                                                        \
  __builtin_amdgcn_global_load_lds((const __attribute__((address_space(1))) unsigned*)    \
                                       (const void*)(g),                                  \
                                   (__attribute__((address_space(3))) unsigned*)(void*)(l),\
                                   16, 0, 0)

// ============================================================
// prep: zero attn-map, mask counts, padded float4 mask table
// ============================================================
__global__ __launch_bounds__(256) void prep_kernel(const float* __restrict__ mask,
                                                   float* __restrict__ amap,
                                                   float* __restrict__ cnt,
                                                   float4* __restrict__ msk4) {
  int t = threadIdx.x;
  for (int i = t; i < 2 * SEQ; i += 256) amap[i] = 0.f;
  for (int i = t; i < 512; i += 256) {
    float4 v;
    v.x = (i < XS) ? mask[i] : 0.f;
    v.y = (i < XS) ? mask[XS + i] : 0.f;
    v.z = (i < XS) ? 1.f : 0.f;
    v.w = 0.f;
    msk4[i] = v;
  }
  float c0 = 0.f, c1 = 0.f;
  for (int i = t; i < XS; i += 256) { c0 += mask[i]; c1 += mask[XS + i]; }
  __shared__ float red0[256];
  __shared__ float red1[256];
  red0[t] = c0; red1[t] = c1;
  __syncthreads();
  for (int off = 128; off > 0; off >>= 1) {
    if (t < off) { red0[t] += red0[t + off]; red1[t] += red1[t + off]; }
    __syncthreads();
  }
  if (t == 0) { cnt[0] = red0[0]; cnt[1] = red1[0]; }
}

// zero V^T tail columns (keys SEQ..SEQP)
__global__ __launch_bounds__(256) void padzero(unsigned short* __restrict__ vt) {
  const int pad = SEQP - SEQ;
  const int total = DIM * pad;
  for (int i = blockIdx.x * 256 + threadIdx.x; i < total; i += gridDim.x * 256) {
    const int d = i / pad, c = i - d * pad;
    vt[(size_t)d * SEQP + SEQ + c] = 0;
  }
}

// f32 -> bf16 (RNE), vectorized
__global__ __launch_bounds__(256) void to_bf16(const float* __restrict__ in,
                                               unsigned short* __restrict__ out, int n4) {
  for (int i = blockIdx.x * 256 + threadIdx.x; i < n4; i += gridDim.x * 256) {
    const float4 v = ((const float4*)in)[i];
    ushort4 o;
    o.x = f2bf(v.x); o.y = f2bf(v.y); o.z = f2bf(v.z); o.w = f2bf(v.w);
    ((ushort4*)out)[i] = o;
  }
}

// 4 weight matrices in one launch (z selects)
__global__ __launch_bounds__(256) void to_bf16_w(const float* __restrict__ W0, const float* __restrict__ W1,
                                                 const float* __restrict__ W2, const float* __restrict__ W3,
                                                 unsigned short* __restrict__ o0, unsigned short* __restrict__ o1,
                                                 unsigned short* __restrict__ o2, unsigned short* __restrict__ o3,
                                                 int n4) {
  const int z = blockIdx.z;
  const float* in = (z == 0) ? W0 : (z == 1) ? W1 : (z == 2) ? W2 : W3;
  unsigned short* out = (z == 0) ? o0 : (z == 1) ? o1 : (z == 2) ? o2 : o3;
  for (int i = blockIdx.x * 256 + threadIdx.x; i < n4; i += gridDim.x * 256) {
    const float4 v = ((const float4*)in)[i];
    ushort4 o;
    o.x = f2bf(v.x); o.y = f2bf(v.y); o.z = f2bf(v.z); o.w = f2bf(v.w);
    ((ushort4*)out)[i] = o;
  }
}

// ============================================================
// combined QKV MFMA GEMM (NT): z=0 -> Q f32, z=1 -> K f32, z=2 -> V^T bf16
// ============================================================
__global__ __launch_bounds__(256) void gemm_qkv(const unsigned short* __restrict__ A,
                                                const unsigned short* __restrict__ B0,
                                                const unsigned short* __restrict__ B1,
                                                const unsigned short* __restrict__ B2,
                                                const float* __restrict__ bq,
                                                const float* __restrict__ bk,
                                                const float* __restrict__ bv,
                                                float* __restrict__ o0,
                                                float* __restrict__ o1,
                                                unsigned short* __restrict__ vtout,
                                                int M) {
  __shared__ unsigned short As[128 * 64];
  __shared__ unsigned short Bs[128 * 64];
  const int z = blockIdx.z;
  const unsigned short* B = (z == 0) ? B0 : (z == 1) ? B1 : B2;
  const float* bias = (z == 0) ? bq : (z == 1) ? bk : bv;
  const int t    = threadIdx.x;
  const int lane = t & 63;
  const int w    = t >> 6;
  const int wr   = w >> 1, wc = w & 1;
  const int bm = blockIdx.x * 128, bn = blockIdx.y * 128;
  const int lq = lane & 15, lg = lane >> 4;
  f32x4 acc[4][4] = {};
  for (int k0 = 0; k0 < DIM; k0 += 64) {
#pragma unroll
    for (int i = 0; i < 4; ++i) {
      const int idx = i * 256 + t;
      const int row = idx >> 3;
      const int c8  = (idx & 7) * 8;
      const int ga  = min(bm + row, M - 1);
      GLD16(A + (size_t)ga * DIM + k0 + c8, As + idx * 8);
      const int gb  = bn + row;
      GLD16(B + (size_t)gb * DIM + k0 + c8, Bs + idx * 8);
    }
    __syncthreads();
#pragma unroll
    for (int kk = 0; kk < 2; ++kk) {
      bf16x8 af[4], bf[4];
#pragma unroll
      for (int m = 0; m < 4; ++m)
        af[m] = *(const bf16x8*)(As + (wr * 64 + m * 16 + lq) * 64 + kk * 32 + lg * 8);
#pragma unroll
      for (int n = 0; n < 4; ++n)
        bf[n] = *(const bf16x8*)(Bs + (wc * 64 + n * 16 + lq) * 64 + kk * 32 + lg * 8);
#pragma unroll
      for (int m = 0; m < 4; ++m)
#pragma unroll
        for (int n = 0; n < 4; ++n)
          acc[m][n] = __builtin_amdgcn_mfma_f32_16x16x32_bf16(af[m], bf[n], acc[m][n], 0, 0, 0);
    }
    __syncthreads();
  }
#pragma unroll
  for (int n = 0; n < 4; ++n) {
    const int col = bn + wc * 64 + n * 16 + lq;
    const float bv2 = bias[col];
#pragma unroll
    for (int m = 0; m < 4; ++m) {
      const int rm = bm + wr * 64 + m * 16 + lg * 4;
      if (z < 2) {
        float* C = (z == 0) ? o0 : o1;
#pragma unroll
        for (int r = 0; r < 4; ++r) {
          const int row = rm + r;
          if (row < M) C[(size_t)row * DIM + col] = acc[m][n][r] + bv2;
        }
      } else {
        if (rm < M) {
          bf16x4 o;
#pragma unroll
          for (int r = 0; r < 4; ++r) o[r] = (short)f2bf(acc[m][n][r] + bv2);
          *(bf16x4*)(vtout + (size_t)col * SEQP + rm) = o;
        }
      }
    }
  }
}

// ============================================================
// single-output GEMM for the final projection (f32 out)
// ============================================================
__global__ __launch_bounds__(256) void gemm_mfma(const unsigned short* __restrict__ A,
                                                 const unsigned short* __restrict__ B,
                                                 const float* __restrict__ bias,
                                                 float* __restrict__ C, int M) {
  __shared__ unsigned short As[128 * 64];
  __shared__ unsigned short Bs[128 * 64];
  const int t    = threadIdx.x;
  const int lane = t & 63;
  const int w    = t >> 6;
  const int wr   = w >> 1, wc = w & 1;
  const int bm = blockIdx.x * 128, bn = blockIdx.y * 128;
  const int lq = lane & 15, lg = lane >> 4;
  f32x4 acc[4][4] = {};
  for (int k0 = 0; k0 < DIM; k0 += 64) {
#pragma unroll
    for (int i = 0; i < 4; ++i) {
      const int idx = i * 256 + t;
      const int row = idx >> 3;
      const int c8  = (idx & 7) * 8;
      const int ga  = min(bm + row, M - 1);
      GLD16(A + (size_t)ga * DIM + k0 + c8, As + idx * 8);
      const int gb  = bn + row;
      GLD16(B + (size_t)gb * DIM + k0 + c8, Bs + idx * 8);
    }
    __syncthreads();
#pragma unroll
    for (int kk = 0; kk < 2; ++kk) {
      bf16x8 af[4], bf[4];
#pragma unroll
      for (int m = 0; m < 4; ++m)
        af[m] = *(const bf16x8*)(As + (wr * 64 + m * 16 + lq) * 64 + kk * 32 + lg * 8);
#pragma unroll
      for (int n = 0; n < 4; ++n)
        bf[n] = *(const bf16x8*)(Bs + (wc * 64 + n * 16 + lq) * 64 + kk * 32 + lg * 8);
#pragma unroll
      for (int m = 0; m < 4; ++m)
#pragma unroll
        for (int n = 0; n < 4; ++n)
          acc[m][n] = __builtin_amdgcn_mfma_f32_16x16x32_bf16(af[m], bf[n], acc[m][n], 0, 0, 0);
    }
    __syncthreads();
  }
#pragma unroll
  for (int n = 0; n < 4; ++n) {
    const int col = bn + wc * 64 + n * 16 + lq;
    const float bv = bias[col];
#pragma unroll
    for (int m = 0; m < 4; ++m) {
      const int rm = bm + wr * 64 + m * 16 + lg * 4;
#pragma unroll
      for (int r = 0; r < 4; ++r) {
        const int row = rm + r;
        if (row < M) C[(size_t)row * DIM + col] = acc[m][n][r] + bv;
      }
    }
  }
}

// ============================================================
// RMSNorm + RoPE for Q and K in one launch (blockIdx.y selects)
// ============================================================
__global__ __launch_bounds__(256) void rms_rope2(const float* __restrict__ qy,
                                                 const float* __restrict__ ky,
                                                 const float* __restrict__ gq,
                                                 const float* __restrict__ gk,
                                                 const float* __restrict__ fcos,
                                                 const float* __restrict__ fsin,
                                                 unsigned short* __restrict__ qout,
                                                 unsigned short* __restrict__ kout) {
  const int z = blockIdx.y;
  const float* y = z ? ky : qy;
  const float* g = z ? gk : gq;
  unsigned short* outb = z ? kout : qout;
  const float scale = z ? 1.0f : 0.08838834764831845f;  // 1/sqrt(128) folded into q
  const int s = blockIdx.x;
  const float* row = y + (size_t)s * DIM;
  const int t = threadIdx.x;
  float ss = 0.f;
  for (int i = t; i < DIM / 4; i += 256) {
    const float4 v = ((const float4*)row)[i];
    ss += v.x * v.x + v.y * v.y + v.z * v.z + v.w * v.w;
  }
#pragma unroll
  for (int off = 1; off < 64; off <<= 1) ss += __shfl_xor(ss, off);
  __shared__ float wred[4];
  if ((t & 63) == 0) wred[t >> 6] = ss;
  __syncthreads();
  const float tot = wred[0] + wred[1] + wred[2] + wred[3];
  const float rs = rsqrtf(tot * (1.0f / DIM) + 1e-6f);
  const int fi  = s / HHWW;
  const int rem = s - fi * HHWW;
  const int hi  = rem / WWc;
  const int wi  = rem - hi * WWc;
  for (int p = t; p < DIM / 2; p += 256) {
    const int head = p >> 6;
    const int c    = p & 63;
    const int idx  = head * HD + 2 * c;
    const int trow = (c < C0c) ? fi : ((c < C0c + C1c) ? hi : wi);
    const float co = fcos[trow * CH + c];
    const float si = fsin[trow * CH + c];
    const float a  = row[idx] * rs * g[idx];
    const float b  = row[idx + 1] * rs * g[idx + 1];
    ushort2 pr;
    pr.x = f2bf((a * co - b * si) * scale);
    pr.y = f2bf((a * si + b * co) * scale);
    *(ushort2*)(outb + (size_t)s * DIM + idx) = pr;
  }
}

// ============================================================
// Flash attention v4: KVB=32, 35 KB LDS -> 4 blocks/CU, single
// generation (828 blocks <= 1024 capacity). 64 q/block, 16 q/wave.
// Defer-max, map reuses main-frame p, cvt_pk P, reg-prefetch.
// ============================================================
#define TILE_BODY(KB_, MAP_, LAST_, PRE_)                                               \
  {                                                                                     \
    const int kb_ = (KB_);                                                              \
    f32x4 sacc[2] = {};                                                                 \
    _Pragma("unroll")                                                                   \
    for (int kbi = 0; kbi < 2; ++kbi) {                                                 \
      const int krow = kbi * 16 + lq;                                                   \
      _Pragma("unroll")                                                                 \
      for (int c = 0; c < 4; ++c) {                                                     \
        const bf16x8 kf = *(const bf16x8*)((char*)Ks + krow * 256 +                     \
                            (((c * 4 + lg) ^ (krow & 7)) * 16));                        \
        sacc[kbi] = __builtin_amdgcn_mfma_f32_16x16x32_bf16(kf, qf[c], sacc[kbi], 0, 0, 0); \
      }                                                                                 \
    }                                                                                   \
    if (PRE_) {                                                                         \
      const int kbn = kb_ + KVB;                                                        \
      _Pragma("unroll")                                                                 \
      for (int j = 0; j < 2; ++j) {                                                     \
        const int ck = t + j * 256;                                                     \
        const int kr = ck >> 4, ks2 = ck & 15;                                          \
        stK[j] = *(const bf16x8*)(kh + (size_t)min(kbn + kr, SEQ - 1) * DIM + ks2 * 8); \
        const int vd = ck >> 2, vs2 = ck & 3;                                           \
        stV[j] = *(const bf16x8*)(vh + (size_t)vd * SEQP + kbn + vs2 * 8);              \
      }                                                                                 \
    }                                                                                   \
    float sv[8];                                                                        \
    float mt = -1e30f;                                                                  \
    _Pragma("unroll")                                                                   \
    for (int i = 0; i < 8; ++i) {                                                       \
      float v = sacc[i >> 2][i & 3];                                                    \
      if (LAST_) {                                                                      \
        const int key = kb_ + (i >> 2) * 16 + lg * 4 + (i & 3);                         \
        if (key >= SEQ) v = -1e30f;                                                     \
      }                                                                                 \
      sv[i] = v;                                                                        \
      mt = fmaxf(mt, v);                                                                \
    }                                                                                   \
    mt = fmaxf(mt, __shfl_xor(mt, 16));                                                 \
    mt = fmaxf(mt, __shfl_xor(mt, 32));                                                 \
    const bool need = __any(mt > m_run + 8.f);                                          \
    if (need) {                                                                         \
      const float m_new = fmaxf(m_run, mt);                                             \
      const float alpha = __expf(m_run - m_new);                                        \
      m_run = m_new;                                                                    \
      l_run *= alpha;                                                                   \
      _Pragma("unroll")                                                                 \
      for (int db = 0; db < 8; ++db) {                                                  \
        acc[db][0] *= alpha; acc[db][1] *= alpha;                                       \
        acc[db][2] *= alpha; acc[db][3] *= alpha;                                       \
      }                                                                                 \
      if (MAP_) { d2 *= alpha; n0 *= alpha; n1 *= alpha; }                              \
    }                                                                                   \
    float ps = 0.f;                                                                     \
    _Pragma("unroll")                                                                   \
    for (int i = 0; i < 8; ++i) { sv[i] = __expf(sv[i] - m_run); ps += sv[i]; }         \
    ps += __shfl_xor(ps, 16);                                                           \
    ps += __shfl_xor(ps, 32);                                                           \
    l_run += ps;                                                                        \
    if (MAP_) {                                                                         \
      _Pragma("unroll")                                                                 \
      for (int i = 0; i < 8; ++i) {                                                     \
        const int key = kb_ + (i >> 2) * 16 + lg * 4 + (i & 3);                         \
        const float4 mv = Msk[key];                                                     \
        n0 = fmaf(sv[i], mv.x, n0);                                                     \
        n1 = fmaf(sv[i], mv.y, n1);                                                     \
        d2 = fmaf(sv[i], mv.z, d2);                                                     \
      }                                                                                 \
    }                                                                                   \
    _Pragma("unroll")                                                                   \
    for (int kbi = 0; kbi < 2; ++kbi) {                                                 \
      unsigned r0, r1;                                                                  \
      asm("v_cvt_pk_bf16_f32 %0, %1, %2" : "=v"(r0) : "v"(sv[kbi * 4 + 0]), "v"(sv[kbi * 4 + 1])); \
      asm("v_cvt_pk_bf16_f32 %0, %1, %2" : "=v"(r1) : "v"(sv[kbi * 4 + 2]), "v"(sv[kbi * 4 + 3])); \
      uint2 pw; pw.x = r0; pw.y = r1;                                                   \
      *(uint2*)&P[lq][kbi * 16 + lg * 4] = pw;                                          \
    }                                                                                   \
    {                                                                                   \
      const bf16x8 pf = *(const bf16x8*)&P[lq][lg * 8];                                 \
      _Pragma("unroll")                                                                 \
      for (int db = 0; db < 8; ++db) {                                                  \
        const bf16x8 vf = *(const bf16x8*)(Vs + (db * 16 + lq) * VP + lg * 8);          \
        acc[db] = __builtin_amdgcn_mfma_f32_16x16x32_bf16(vf, pf, acc[db], 0, 0, 0);    \
      }                                                                                 \
    }                                                                                   \
    if (PRE_) {                                                                         \
      __syncthreads();                                                                  \
      _Pragma("unroll")                                                                 \
      for (int j = 0; j < 2; ++j) {                                                     \
        const int ck = t + j * 256;                                                     \
        const int kr = ck >> 4, ks2 = ck & 15;                                          \
        *(bf16x8*)((char*)Ks + kr * 256 + ((ks2 ^ (kr & 7)) * 16)) = stK[j];            \
        const int vd = ck >> 2, vs2 = ck & 3;                                           \
        *(bf16x8*)(Vs + vd * VP + vs2 * 8) = stV[j];                                    \
      }                                                                                 \
      __syncthreads();                                                                  \
    }                                                                                   \
  }

__global__ __launch_bounds__(256, 4) void flash_mfma(const unsigned short* __restrict__ qbuf,
                                                     const unsigned short* __restrict__ kbuf,
                                                     const unsigned short* __restrict__ vt,
                                                     const float4* __restrict__ msk4,
                                                     const float* __restrict__ cnt,
                                                     unsigned short* __restrict__ ob,
                                                     float* __restrict__ amap) {
  const int h    = blockIdx.y;
  const int t    = threadIdx.x;
  const int w    = t >> 6;
  const int lane = t & 63;
  const int lq   = lane & 15, lg = lane >> 4;
  const int qbase = blockIdx.x * 64 + w * 16;

  __shared__ __align__(16) unsigned short Ks[KVB * 128];     // [key][dim], XOR-swizzled
  __shared__ __align__(16) unsigned short Vs[128 * VP];      // [dim][key], padded pitch
  __shared__ __align__(16) unsigned short Plds[4][16][72];
  __shared__ float4 Msk[512];
  unsigned short (*P)[72] = Plds[w];

  const unsigned short* kh = kbuf + h * HD;
  const unsigned short* vh = vt + (size_t)(h * HD) * SEQP;

  for (int i = t; i < 512; i += 256) Msk[i] = msk4[i];

  const int qsrc = min(qbase + lq, SEQ - 1);
  bf16x8 qf[4];
#pragma unroll
  for (int c = 0; c < 4; ++c)
    qf[c] = *(const bf16x8*)(qbuf + (size_t)qsrc * DIM + h * HD + c * 32 + lg * 8);

  f32x4 acc[8] = {};
  float m_run = -1e30f, l_run = 0.f;
  float d2 = 0.f, n0 = 0.f, n1 = 0.f;

  bf16x8 stK[2], stV[2];
  // prologue: stage tile 0
#pragma unroll
  for (int j = 0; j < 2; ++j) {
    const int ck = t + j * 256;
    const int kr = ck >> 4, ks2 = ck & 15;
    stK[j] = *(const bf16x8*)(kh + (size_t)min(kr, SEQ - 1) * DIM + ks2 * 8);
    const int vd = ck >> 2, vs2 = ck & 3;
    stV[j] = *(const bf16x8*)(vh + (size_t)vd * SEQP + vs2 * 8);
  }
#pragma unroll
  for (int j = 0; j < 2; ++j) {
    const int ck = t + j * 256;
    const int kr = ck >> 4, ks2 = ck & 15;
    *(bf16x8*)((char*)Ks + kr * 256 + ((ks2 ^ (kr & 7)) * 16)) = stK[j];
    const int vd = ck >> 2, vs2 = ck & 3;
    *(bf16x8*)(Vs + vd * VP + vs2 * 8) = stV[j];
  }
  __syncthreads();

  for (int tile = 0; tile < 16; ++tile)         TILE_BODY(tile * KVB, true,  false, true);
  for (int tile = 16; tile < NT - 1; ++tile)    TILE_BODY(tile * KVB, false, false, true);
  TILE_BODY((NT - 1) * KVB, false, true, false);

  // epilogue: O write
  const int qrow = qbase + lq;
  if (qrow < SEQ) {
    const float inv = 1.f / l_run;
#pragma unroll
    for (int db = 0; db < 8; ++db) {
      bf16x4 o;
#pragma unroll
      for (int r = 0; r < 4; ++r) o[r] = (short)f2bf(acc[db][r] * inv);
      *(bf16x4*)(ob + (size_t)qrow * DIM + h * HD + db * 16 + lg * 4) = o;
    }
  }
  // attn-map: lane groups share the same frame -> plain sums
  d2 += __shfl_xor(d2, 16); d2 += __shfl_xor(d2, 32);
  n0 += __shfl_xor(n0, 16); n0 += __shfl_xor(n0, 32);
  n1 += __shfl_xor(n1, 16); n1 += __shfl_xor(n1, 32);
  if (lane < 16 && qrow < SEQ) {
    const float invd = 1.f / (d2 * (float)HEADS);
    atomicAdd(&amap[qrow],       n0 * invd / cnt[0]);
    atomicAdd(&amap[SEQ + qrow], n1 * invd / cnt[1]);
  }
}

// ============================================================
extern "C" void kernel_launch(void* const* d_in, const int* in_sizes, int n_in,
                              void* d_out, int out_size, void* d_ws, size_t ws_size,
                              hipStream_t stream) {
  const float* x    = (const float*)d_in[0];
  const float* Wq   = (const float*)d_in[1];
  const float* bq   = (const float*)d_in[2];
  const float* Wk   = (const float*)d_in[3];
  const float* bk   = (const float*)d_in[4];
  const float* Wv   = (const float*)d_in[5];
  const float* bv   = (const float*)d_in[6];
  const float* Wo   = (const float*)d_in[7];
  const float* bo   = (const float*)d_in[8];
  const float* gq   = (const float*)d_in[9];
  const float* gk   = (const float*)d_in[10];
  const float* fc   = (const float*)d_in[11];
  const float* fs   = (const float*)d_in[12];
  const float* mask = (const float*)d_in[13];

  float* out  = (float*)d_out;
  float* amap = out + SD;
  float* f32a = out;                                    // Q f32 scratch in d_out

  float* f32b        = (float*)d_ws;                    // SD f32 (K); later ob
  unsigned short* xb = (unsigned short*)(f32b + SD);    // SD bf16
  unsigned short* qb = xb + SD;
  unsigned short* kb = qb + SD;
  unsigned short* vt = kb + SD;                         // DIM*SEQP bf16
  unsigned short* wqb = vt + (size_t)DIM * SEQP;        // 4x DIM*DIM bf16
  unsigned short* wkb = wqb + (size_t)DIM * DIM;
  unsigned short* wvb = wkb + (size_t)DIM * DIM;
  unsigned short* wob = wvb + (size_t)DIM * DIM;
  float4* msk4 = (float4*)(wob + (size_t)DIM * DIM);    // 512
  float* cnt  = (float*)(msk4 + 512);
  unsigned short* ob = (unsigned short*)f32b;           // alias: f32b dead by then

  prep_kernel<<<1, 256, 0, stream>>>(mask, amap, cnt, msk4);
  padzero<<<64, 256, 0, stream>>>(vt);
  to_bf16<<<2048, 256, 0, stream>>>(x, xb, (int)(SD / 4));
  constexpr int W4 = DIM * DIM / 4;
  to_bf16_w<<<dim3(512, 1, 4), 256, 0, stream>>>(Wq, Wk, Wv, Wo, wqb, wkb, wvb, wob, W4);

  const dim3 gg((SEQ + 127) / 128, DIM / 128, 3);
  gemm_qkv<<<gg, 256, 0, stream>>>(xb, wqb, wkb, wvb, bq, bk, bv, f32a, f32b, vt, SEQ);

  rms_rope2<<<dim3(SEQ, 2), 256, 0, stream>>>(f32a, f32b, gq, gk, fc, fs, qb, kb);

  const dim3 fg((SEQ + 63) / 64, HEADS);
  flash_mfma<<<fg, 256, 0, stream>>>(qb, kb, vt, msk4, cnt, ob, amap);

  const dim3 go((SEQ + 127) / 128, DIM / 128);
  gemm_mfma<<<go, 256, 0, stream>>>(ob, wob, bo, out, SEQ);
}

// Round 6
// 445.897 us; speedup vs baseline: 23.8171x; 1.0477x over previous
//
#include <hip/hip_runtime.h>
#include <hip/hip_bf16.h>
#include <math.h>

// ---- problem constants ----
constexpr int SEQ   = 4356;
constexpr int DIM   = 1536;
constexpr int HEADS = 12;
constexpr int HD    = 128;
constexpr int CH    = 64;           // HD/2 rope channels
constexpr int C0c   = 22;
constexpr int C1c   = 21;
constexpr int WWc   = 22;
constexpr int HHWW  = 484;
constexpr int XS    = 484;
constexpr int KVB   = 32;
constexpr int NT    = (SEQ + KVB - 1) / KVB;   // 137 tiles
constexpr int SEQP  = 4416;                    // padded V^T row pitch
constexpr size_t SD = (size_t)SEQ * DIM;

typedef float f32x4 __attribute__((ext_vector_type(4)));
typedef short bf16x8 __attribute__((ext_vector_type(8)));
typedef short bf16x4 __attribute__((ext_vector_type(4)));

__device__ inline unsigned short f2bf(float f) {
  union { float f; unsigned u; } x; x.f = f;
  return (unsigned short)((x.u + 0x7FFFu + ((x.u >> 16) & 1u)) >> 16);
}

#define GLD16(g, l)                                                                        \
  __builtin_amdgcn_global_load_lds((const __attribute__((address_space(1))) unsigned*)    \
                                       (const void*)(g),                                  \
                                   (__attribute__((address_space(3))) unsigned*)(void*)(l),\
                                   16, 0, 0)

// ============================================================
// prep: zero attn-map, mask counts, padded float4 mask table
// ============================================================
__global__ __launch_bounds__(256) void prep_kernel(const float* __restrict__ mask,
                                                   float* __restrict__ amap,
                                                   float* __restrict__ cnt,
                                                   float4* __restrict__ msk4) {
  int t = threadIdx.x;
  for (int i = t; i < 2 * SEQ; i += 256) amap[i] = 0.f;
  for (int i = t; i < 512; i += 256) {
    float4 v;
    v.x = (i < XS) ? mask[i] : 0.f;
    v.y = (i < XS) ? mask[XS + i] : 0.f;
    v.z = (i < XS) ? 1.f : 0.f;
    v.w = 0.f;
    msk4[i] = v;
  }
  float c0 = 0.f, c1 = 0.f;
  for (int i = t; i < XS; i += 256) { c0 += mask[i]; c1 += mask[XS + i]; }
  __shared__ float red0[256];
  __shared__ float red1[256];
  red0[t] = c0; red1[t] = c1;
  __syncthreads();
  for (int off = 128; off > 0; off >>= 1) {
    if (t < off) { red0[t] += red0[t + off]; red1[t] += red1[t + off]; }
    __syncthreads();
  }
  if (t == 0) { cnt[0] = red0[0]; cnt[1] = red1[0]; }
}

// zero V^T tail columns (keys SEQ..SEQP)
__global__ __launch_bounds__(256) void padzero(unsigned short* __restrict__ vt) {
  const int pad = SEQP - SEQ;
  const int total = DIM * pad;
  for (int i = blockIdx.x * 256 + threadIdx.x; i < total; i += gridDim.x * 256) {
    const int d = i / pad, c = i - d * pad;
    vt[(size_t)d * SEQP + SEQ + c] = 0;
  }
}

// f32 -> bf16 (RNE), vectorized
__global__ __launch_bounds__(256) void to_bf16(const float* __restrict__ in,
                                               unsigned short* __restrict__ out, int n4) {
  for (int i = blockIdx.x * 256 + threadIdx.x; i < n4; i += gridDim.x * 256) {
    const float4 v = ((const float4*)in)[i];
    ushort4 o;
    o.x = f2bf(v.x); o.y = f2bf(v.y); o.z = f2bf(v.z); o.w = f2bf(v.w);
    ((ushort4*)out)[i] = o;
  }
}

// 4 weight matrices in one launch (z selects)
__global__ __launch_bounds__(256) void to_bf16_w(const float* __restrict__ W0, const float* __restrict__ W1,
                                                 const float* __restrict__ W2, const float* __restrict__ W3,
                                                 unsigned short* __restrict__ o0, unsigned short* __restrict__ o1,
                                                 unsigned short* __restrict__ o2, unsigned short* __restrict__ o3,
                                                 int n4) {
  const int z = blockIdx.z;
  const float* in = (z == 0) ? W0 : (z == 1) ? W1 : (z == 2) ? W2 : W3;
  unsigned short* out = (z == 0) ? o0 : (z == 1) ? o1 : (z == 2) ? o2 : o3;
  for (int i = blockIdx.x * 256 + threadIdx.x; i < n4; i += gridDim.x * 256) {
    const float4 v = ((const float4*)in)[i];
    ushort4 o;
    o.x = f2bf(v.x); o.y = f2bf(v.y); o.z = f2bf(v.z); o.w = f2bf(v.w);
    ((ushort4*)out)[i] = o;
  }
}

// ============================================================
// combined QKV MFMA GEMM (NT): z=0 -> Q f32, z=1 -> K f32, z=2 -> V^T bf16
// ============================================================
__global__ __launch_bounds__(256) void gemm_qkv(const unsigned short* __restrict__ A,
                                                const unsigned short* __restrict__ B0,
                                                const unsigned short* __restrict__ B1,
                                                const unsigned short* __restrict__ B2,
                                                const float* __restrict__ bq,
                                                const float* __restrict__ bk,
                                                const float* __restrict__ bv,
                                                float* __restrict__ o0,
                                                float* __restrict__ o1,
                                                unsigned short* __restrict__ vtout,
                                                int M) {
  __shared__ unsigned short As[128 * 64];
  __shared__ unsigned short Bs[128 * 64];
  const int z = blockIdx.z;
  const unsigned short* B = (z == 0) ? B0 : (z == 1) ? B1 : B2;
  const float* bias = (z == 0) ? bq : (z == 1) ? bk : bv;
  const int t    = threadIdx.x;
  const int lane = t & 63;
  const int w    = t >> 6;
  const int wr   = w >> 1, wc = w & 1;
  const int bm = blockIdx.x * 128, bn = blockIdx.y * 128;
  const int lq = lane & 15, lg = lane >> 4;
  f32x4 acc[4][4] = {};
  for (int k0 = 0; k0 < DIM; k0 += 64) {
#pragma unroll
    for (int i = 0; i < 4; ++i) {
      const int idx = i * 256 + t;
      const int row = idx >> 3;
      const int c8  = (idx & 7) * 8;
      const int ga  = min(bm + row, M - 1);
      GLD16(A + (size_t)ga * DIM + k0 + c8, As + idx * 8);
      const int gb  = bn + row;
      GLD16(B + (size_t)gb * DIM + k0 + c8, Bs + idx * 8);
    }
    __syncthreads();
#pragma unroll
    for (int kk = 0; kk < 2; ++kk) {
      bf16x8 af[4], bf[4];
#pragma unroll
      for (int m = 0; m < 4; ++m)
        af[m] = *(const bf16x8*)(As + (wr * 64 + m * 16 + lq) * 64 + kk * 32 + lg * 8);
#pragma unroll
      for (int n = 0; n < 4; ++n)
        bf[n] = *(const bf16x8*)(Bs + (wc * 64 + n * 16 + lq) * 64 + kk * 32 + lg * 8);
#pragma unroll
      for (int m = 0; m < 4; ++m)
#pragma unroll
        for (int n = 0; n < 4; ++n)
          acc[m][n] = __builtin_amdgcn_mfma_f32_16x16x32_bf16(af[m], bf[n], acc[m][n], 0, 0, 0);
    }
    __syncthreads();
  }
#pragma unroll
  for (int n = 0; n < 4; ++n) {
    const int col = bn + wc * 64 + n * 16 + lq;
    const float bv2 = bias[col];
#pragma unroll
    for (int m = 0; m < 4; ++m) {
      const int rm = bm + wr * 64 + m * 16 + lg * 4;
      if (z < 2) {
        float* C = (z == 0) ? o0 : o1;
#pragma unroll
        for (int r = 0; r < 4; ++r) {
          const int row = rm + r;
          if (row < M) C[(size_t)row * DIM + col] = acc[m][n][r] + bv2;
        }
      } else {
        if (rm < M) {
          bf16x4 o;
#pragma unroll
          for (int r = 0; r < 4; ++r) o[r] = (short)f2bf(acc[m][n][r] + bv2);
          *(bf16x4*)(vtout + (size_t)col * SEQP + rm) = o;
        }
      }
    }
  }
}

// ============================================================
// single-output GEMM for the final projection (f32 out)
// ============================================================
__global__ __launch_bounds__(256) void gemm_mfma(const unsigned short* __restrict__ A,
                                                 const unsigned short* __restrict__ B,
                                                 const float* __restrict__ bias,
                                                 float* __restrict__ C, int M) {
  __shared__ unsigned short As[128 * 64];
  __shared__ unsigned short Bs[128 * 64];
  const int t    = threadIdx.x;
  const int lane = t & 63;
  const int w    = t >> 6;
  const int wr   = w >> 1, wc = w & 1;
  const int bm = blockIdx.x * 128, bn = blockIdx.y * 128;
  const int lq = lane & 15, lg = lane >> 4;
  f32x4 acc[4][4] = {};
  for (int k0 = 0; k0 < DIM; k0 += 64) {
#pragma unroll
    for (int i = 0; i < 4; ++i) {
      const int idx = i * 256 + t;
      const int row = idx >> 3;
      const int c8  = (idx & 7) * 8;
      const int ga  = min(bm + row, M - 1);
      GLD16(A + (size_t)ga * DIM + k0 + c8, As + idx * 8);
      const int gb  = bn + row;
      GLD16(B + (size_t)gb * DIM + k0 + c8, Bs + idx * 8);
    }
    __syncthreads();
#pragma unroll
    for (int kk = 0; kk < 2; ++kk) {
      bf16x8 af[4], bf[4];
#pragma unroll
      for (int m = 0; m < 4; ++m)
        af[m] = *(const bf16x8*)(As + (wr * 64 + m * 16 + lq) * 64 + kk * 32 + lg * 8);
#pragma unroll
      for (int n = 0; n < 4; ++n)
        bf[n] = *(const bf16x8*)(Bs + (wc * 64 + n * 16 + lq) * 64 + kk * 32 + lg * 8);
#pragma unroll
      for (int m = 0; m < 4; ++m)
#pragma unroll
        for (int n = 0; n < 4; ++n)
          acc[m][n] = __builtin_amdgcn_mfma_f32_16x16x32_bf16(af[m], bf[n], acc[m][n], 0, 0, 0);
    }
    __syncthreads();
  }
#pragma unroll
  for (int n = 0; n < 4; ++n) {
    const int col = bn + wc * 64 + n * 16 + lq;
    const float bv = bias[col];
#pragma unroll
    for (int m = 0; m < 4; ++m) {
      const int rm = bm + wr * 64 + m * 16 + lg * 4;
#pragma unroll
      for (int r = 0; r < 4; ++r) {
        const int row = rm + r;
        if (row < M) C[(size_t)row * DIM + col] = acc[m][n][r] + bv;
      }
    }
  }
}

// ============================================================
// RMSNorm + RoPE for Q and K in one launch (blockIdx.y selects)
// ============================================================
__global__ __launch_bounds__(256) void rms_rope2(const float* __restrict__ qy,
                                                 const float* __restrict__ ky,
                                                 const float* __restrict__ gq,
                                                 const float* __restrict__ gk,
                                                 const float* __restrict__ fcos,
                                                 const float* __restrict__ fsin,
                                                 unsigned short* __restrict__ qout,
                                                 unsigned short* __restrict__ kout) {
  const int z = blockIdx.y;
  const float* y = z ? ky : qy;
  const float* g = z ? gk : gq;
  unsigned short* outb = z ? kout : qout;
  const float scale = z ? 1.0f : 0.08838834764831845f;  // 1/sqrt(128) folded into q
  const int s = blockIdx.x;
  const float* row = y + (size_t)s * DIM;
  const int t = threadIdx.x;
  float ss = 0.f;
  for (int i = t; i < DIM / 4; i += 256) {
    const float4 v = ((const float4*)row)[i];
    ss += v.x * v.x + v.y * v.y + v.z * v.z + v.w * v.w;
  }
#pragma unroll
  for (int off = 1; off < 64; off <<= 1) ss += __shfl_xor(ss, off);
  __shared__ float wred[4];
  if ((t & 63) == 0) wred[t >> 6] = ss;
  __syncthreads();
  const float tot = wred[0] + wred[1] + wred[2] + wred[3];
  const float rs = rsqrtf(tot * (1.0f / DIM) + 1e-6f);
  const int fi  = s / HHWW;
  const int rem = s - fi * HHWW;
  const int hi  = rem / WWc;
  const int wi  = rem - hi * WWc;
  for (int p = t; p < DIM / 2; p += 256) {
    const int head = p >> 6;
    const int c    = p & 63;
    const int idx  = head * HD + 2 * c;
    const int trow = (c < C0c) ? fi : ((c < C0c + C1c) ? hi : wi);
    const float co = fcos[trow * CH + c];
    const float si = fsin[trow * CH + c];
    const float a  = row[idx] * rs * g[idx];
    const float b  = row[idx + 1] * rs * g[idx + 1];
    ushort2 pr;
    pr.x = f2bf((a * co - b * si) * scale);
    pr.y = f2bf((a * si + b * co) * scale);
    *(ushort2*)(outb + (size_t)s * DIM + idx) = pr;
  }
}

// ============================================================
// Flash attention v5: 32 q/wave (2 q-sets share every K/V frag read),
// KVB=32 double-buffered K+V staged via global_load_lds (pre-swizzled
// global source, linear LDS dest), 1 barrier/tile. 128 q/block.
// ============================================================
#define SOFT_QS(QS, SACC, ACC, MAP_, LAST_, KBV)                                           \
  {                                                                                        \
    float sv[8]; float mt = -1e30f;                                                        \
    _Pragma("unroll")                                                                      \
    for (int i = 0; i < 8; ++i) {                                                          \
      float v = SACC[i >> 2][i & 3];                                                       \
      if (LAST_) { const int key = (KBV) + (i >> 2) * 16 + lg * 4 + (i & 3);               \
                   if (key >= SEQ) v = -1e30f; }                                           \
      sv[i] = v; mt = fmaxf(mt, v);                                                        \
    }                                                                                      \
    mt = fmaxf(mt, __shfl_xor(mt, 16));                                                    \
    mt = fmaxf(mt, __shfl_xor(mt, 32));                                                    \
    if (__any(mt > m_run[QS] + 8.f)) {                                                     \
      const float m_new = fmaxf(m_run[QS], mt);                                            \
      const float alpha = __expf(m_run[QS] - m_new);                                       \
      m_run[QS] = m_new; l_run[QS] *= alpha;                                               \
      _Pragma("unroll")                                                                    \
      for (int db = 0; db < 8; ++db) {                                                     \
        ACC[db][0] *= alpha; ACC[db][1] *= alpha;                                          \
        ACC[db][2] *= alpha; ACC[db][3] *= alpha;                                          \
      }                                                                                    \
      if (MAP_) { d2[QS] *= alpha; n0[QS] *= alpha; n1[QS] *= alpha; }                     \
    }                                                                                      \
    float ps = 0.f;                                                                        \
    _Pragma("unroll")                                                                      \
    for (int i = 0; i < 8; ++i) { sv[i] = __expf(sv[i] - m_run[QS]); ps += sv[i]; }        \
    ps += __shfl_xor(ps, 16); ps += __shfl_xor(ps, 32);                                    \
    l_run[QS] += ps;                                                                       \
    if (MAP_) {                                                                            \
      _Pragma("unroll")                                                                    \
      for (int i = 0; i < 8; ++i) {                                                        \
        const int key = (KBV) + (i >> 2) * 16 + lg * 4 + (i & 3);                          \
        const float4 mv = Msk[key];                                                        \
        n0[QS] = fmaf(sv[i], mv.x, n0[QS]);                                                \
        n1[QS] = fmaf(sv[i], mv.y, n1[QS]);                                                \
        d2[QS] = fmaf(sv[i], mv.z, d2[QS]);                                                \
      }                                                                                    \
    }                                                                                      \
    _Pragma("unroll")                                                                      \
    for (int kbi = 0; kbi < 2; ++kbi) {                                                    \
      unsigned r0, r1;                                                                     \
      asm("v_cvt_pk_bf16_f32 %0, %1, %2" : "=v"(r0) : "v"(sv[kbi*4+0]), "v"(sv[kbi*4+1])); \
      asm("v_cvt_pk_bf16_f32 %0, %1, %2" : "=v"(r1) : "v"(sv[kbi*4+2]), "v"(sv[kbi*4+3])); \
      uint2 pw; pw.x = r0; pw.y = r1;                                                      \
      *(uint2*)&Pw[QS][lq][kbi * 16 + lg * 4] = pw;                                        \
    }                                                                                      \
  }

#define TILE_BODY(KB_, MAP_, LAST_, PRE_)                                                  \
  {                                                                                        \
    const int kb_ = (KB_);                                                                 \
    const int cur_ = (kb_ >> 5) & 1;                                                       \
    const unsigned short* Kc = Ks[cur_];                                                   \
    const unsigned short* Vc = Vs[cur_];                                                   \
    if (PRE_) {                                                                            \
      unsigned short* Kn = Ks[cur_ ^ 1];                                                   \
      unsigned short* Vn = Vs[cur_ ^ 1];                                                   \
      const int kbn = kb_ + KVB;                                                           \
      _Pragma("unroll")                                                                    \
      for (int j = 0; j < 2; ++j) {                                                        \
        const int ck = t + j * 256;                                                        \
        const int kr = ck >> 4, ksl = ck & 15;                                             \
        GLD16(kh + (size_t)min(kbn + kr, SEQ - 1) * DIM + ((ksl ^ (kr & 7)) * 8),          \
              Kn + ck * 8);                                                                \
        const int vd = ck >> 2, vsl = ck & 3;                                              \
        GLD16(vh + (size_t)vd * SEQP + kbn + ((vsl ^ ((vd >> 1) & 3)) * 8),                \
              Vn + ck * 8);                                                                \
      }                                                                                    \
    }                                                                                      \
    f32x4 sacc0[2] = {}, sacc1[2] = {};                                                    \
    _Pragma("unroll")                                                                      \
    for (int kbi = 0; kbi < 2; ++kbi) {                                                    \
      const int krow = kbi * 16 + lq;                                                      \
      _Pragma("unroll")                                                                    \
      for (int c = 0; c < 4; ++c) {                                                        \
        const bf16x8 kf = *(const bf16x8*)(Kc + (krow * 16 + ((c * 4 + lg) ^ (krow & 7))) * 8); \
        sacc0[kbi] = __builtin_amdgcn_mfma_f32_16x16x32_bf16(kf, qf0[c], sacc0[kbi], 0, 0, 0);  \
        sacc1[kbi] = __builtin_amdgcn_mfma_f32_16x16x32_bf16(kf, qf1[c], sacc1[kbi], 0, 0, 0);  \
      }                                                                                    \
    }                                                                                      \
    SOFT_QS(0, sacc0, acc0, MAP_, LAST_, kb_)                                              \
    SOFT_QS(1, sacc1, acc1, MAP_, LAST_, kb_)                                              \
    {                                                                                      \
      const bf16x8 pf0 = *(const bf16x8*)&Pw[0][lq][lg * 8];                               \
      const bf16x8 pf1 = *(const bf16x8*)&Pw[1][lq][lg * 8];                               \
      _Pragma("unroll")                                                                    \
      for (int db = 0; db < 8; ++db) {                                                     \
        const int vd = db * 16 + lq;                                                       \
        const bf16x8 vf = *(const bf16x8*)(Vc + (vd * 4 + (lg ^ ((vd >> 1) & 3))) * 8);    \
        acc0[db] = __builtin_amdgcn_mfma_f32_16x16x32_bf16(vf, pf0, acc0[db], 0, 0, 0);    \
        acc1[db] = __builtin_amdgcn_mfma_f32_16x16x32_bf16(vf, pf1, acc1[db], 0, 0, 0);    \
      }                                                                                    \
    }                                                                                      \
    if (PRE_) __syncthreads();                                                             \
  }

__global__ __launch_bounds__(256, 3) void flash_mfma(const unsigned short* __restrict__ qbuf,
                                                     const unsigned short* __restrict__ kbuf,
                                                     const unsigned short* __restrict__ vt,
                                                     const float4* __restrict__ msk4,
                                                     const float* __restrict__ cnt,
                                                     unsigned short* __restrict__ ob,
                                                     float* __restrict__ amap) {
  const int h    = blockIdx.y;
  const int t    = threadIdx.x;
  const int w    = t >> 6;
  const int lane = t & 63;
  const int lq   = lane & 15, lg = lane >> 4;
  const int qbase = blockIdx.x * 128 + w * 32;

  __shared__ __align__(16) unsigned short Ks[2][KVB * 128];  // [key][16 chunks], src-swizzled
  __shared__ __align__(16) unsigned short Vs[2][128 * KVB];  // [dim][4 chunks],  src-swizzled
  __shared__ __align__(16) unsigned short Plds[4][2][16][40];
  __shared__ float4 Msk[512];
  unsigned short (*Pw)[16][40] = Plds[w];

  const unsigned short* kh = kbuf + h * HD;
  const unsigned short* vh = vt + (size_t)(h * HD) * SEQP;

  for (int i = t; i < 512; i += 256) Msk[i] = msk4[i];

  const int qsrc0 = min(qbase + lq, SEQ - 1);
  const int qsrc1 = min(qbase + 16 + lq, SEQ - 1);
  bf16x8 qf0[4], qf1[4];
#pragma unroll
  for (int c = 0; c < 4; ++c) {
    qf0[c] = *(const bf16x8*)(qbuf + (size_t)qsrc0 * DIM + h * HD + c * 32 + lg * 8);
    qf1[c] = *(const bf16x8*)(qbuf + (size_t)qsrc1 * DIM + h * HD + c * 32 + lg * 8);
  }

  f32x4 acc0[8] = {}, acc1[8] = {};
  float m_run[2] = {-1e30f, -1e30f}, l_run[2] = {0.f, 0.f};
  float d2[2] = {0.f, 0.f}, n0[2] = {0.f, 0.f}, n1[2] = {0.f, 0.f};

  // prologue: stage tile 0 into buffer 0
#pragma unroll
  for (int j = 0; j < 2; ++j) {
    const int ck = t + j * 256;
    const int kr = ck >> 4, ksl = ck & 15;
    GLD16(kh + (size_t)min(kr, SEQ - 1) * DIM + ((ksl ^ (kr & 7)) * 8), Ks[0] + ck * 8);
    const int vd = ck >> 2, vsl = ck & 3;
    GLD16(vh + (size_t)vd * SEQP + ((vsl ^ ((vd >> 1) & 3)) * 8), Vs[0] + ck * 8);
  }
  __syncthreads();

  for (int tile = 0; tile < 16; ++tile)         TILE_BODY(tile * KVB, true,  false, true);
  for (int tile = 16; tile < NT - 1; ++tile)    TILE_BODY(tile * KVB, false, false, true);
  TILE_BODY((NT - 1) * KVB, false, true, false);

  // epilogue: O writes
  {
    const int qrow = qbase + lq;
    if (qrow < SEQ) {
      const float inv = 1.f / l_run[0];
#pragma unroll
      for (int db = 0; db < 8; ++db) {
        bf16x4 o;
#pragma unroll
        for (int r = 0; r < 4; ++r) o[r] = (short)f2bf(acc0[db][r] * inv);
        *(bf16x4*)(ob + (size_t)qrow * DIM + h * HD + db * 16 + lg * 4) = o;
      }
    }
  }
  {
    const int qrow = qbase + 16 + lq;
    if (qrow < SEQ) {
      const float inv = 1.f / l_run[1];
#pragma unroll
      for (int db = 0; db < 8; ++db) {
        bf16x4 o;
#pragma unroll
        for (int r = 0; r < 4; ++r) o[r] = (short)f2bf(acc1[db][r] * inv);
        *(bf16x4*)(ob + (size_t)qrow * DIM + h * HD + db * 16 + lg * 4) = o;
      }
    }
  }
  // attn-map: lane groups share the same frame -> plain sums
#pragma unroll
  for (int qs = 0; qs < 2; ++qs) {
    float dd = d2[qs], a0 = n0[qs], a1 = n1[qs];
    dd += __shfl_xor(dd, 16); dd += __shfl_xor(dd, 32);
    a0 += __shfl_xor(a0, 16); a0 += __shfl_xor(a0, 32);
    a1 += __shfl_xor(a1, 16); a1 += __shfl_xor(a1, 32);
    const int qrow = qbase + qs * 16 + lq;
    if (lane < 16 && qrow < SEQ) {
      const float invd = 1.f / (dd * (float)HEADS);
      atomicAdd(&amap[qrow],       a0 * invd / cnt[0]);
      atomicAdd(&amap[SEQ + qrow], a1 * invd / cnt[1]);
    }
  }
}

// ============================================================
extern "C" void kernel_launch(void* const* d_in, const int* in_sizes, int n_in,
                              void* d_out, int out_size, void* d_ws, size_t ws_size,
                              hipStream_t stream) {
  const float* x    = (const float*)d_in[0];
  const float* Wq   = (const float*)d_in[1];
  const float* bq   = (const float*)d_in[2];
  const float* Wk   = (const float*)d_in[3];
  const float* bk   = (const float*)d_in[4];
  const float* Wv   = (const float*)d_in[5];
  const float* bv   = (const float*)d_in[6];
  const float* Wo   = (const float*)d_in[7];
  const float* bo   = (const float*)d_in[8];
  const float* gq   = (const float*)d_in[9];
  const float* gk   = (const float*)d_in[10];
  const float* fc   = (const float*)d_in[11];
  const float* fs   = (const float*)d_in[12];
  const float* mask = (const float*)d_in[13];

  float* out  = (float*)d_out;
  float* amap = out + SD;
  float* f32a = out;                                    // Q f32 scratch in d_out

  float* f32b        = (float*)d_ws;                    // SD f32 (K); later ob
  unsigned short* xb = (unsigned short*)(f32b + SD);    // SD bf16
  unsigned short* qb = xb + SD;
  unsigned short* kb = qb + SD;
  unsigned short* vt = kb + SD;                         // DIM*SEQP bf16
  unsigned short* wqb = vt + (size_t)DIM * SEQP;        // 4x DIM*DIM bf16
  unsigned short* wkb = wqb + (size_t)DIM * DIM;
  unsigned short* wvb = wkb + (size_t)DIM * DIM;
  unsigned short* wob = wvb + (size_t)DIM * DIM;
  float4* msk4 = (float4*)(wob + (size_t)DIM * DIM);    // 512
  float* cnt  = (float*)(msk4 + 512);
  unsigned short* ob = (unsigned short*)f32b;           // alias: f32b dead by then

  prep_kernel<<<1, 256, 0, stream>>>(mask, amap, cnt, msk4);
  padzero<<<64, 256, 0, stream>>>(vt);
  to_bf16<<<2048, 256, 0, stream>>>(x, xb, (int)(SD / 4));
  constexpr int W4 = DIM * DIM / 4;
  to_bf16_w<<<dim3(512, 1, 4), 256, 0, stream>>>(Wq, Wk, Wv, Wo, wqb, wkb, wvb, wob, W4);

  const dim3 gg((SEQ + 127) / 128, DIM / 128, 3);
  gemm_qkv<<<gg, 256, 0, stream>>>(xb, wqb, wkb, wvb, bq, bk, bv, f32a, f32b, vt, SEQ);

  rms_rope2<<<dim3(SEQ, 2), 256, 0, stream>>>(f32a, f32b, gq, gk, fc, fs, qb, kb);

  const dim3 fg((SEQ + 127) / 128, HEADS);
  flash_mfma<<<fg, 256, 0, stream>>>(qb, kb, vt, msk4, cnt, ob, amap);

  const dim3 go((SEQ + 127) / 128, DIM / 128);
  gemm_mfma<<<go, 256, 0, stream>>>(ob, wob, bo, out, SEQ);
}

// Round 7
// 434.132 us; speedup vs baseline: 24.4626x; 1.0271x over previous
//
#include <hip/hip_runtime.h>
#include <hip/hip_bf16.h>
#include <math.h>

// ---- problem constants ----
constexpr int SEQ   = 4356;
constexpr int DIM   = 1536;
constexpr int HEADS = 12;
constexpr int HD    = 128;
constexpr int CH    = 64;           // HD/2 rope channels
constexpr int C0c   = 22;
constexpr int C1c   = 21;
constexpr int WWc   = 22;
constexpr int HHWW  = 484;
constexpr int XS    = 484;
constexpr int KVB   = 32;
constexpr int NT    = (SEQ + KVB - 1) / KVB;   // 137 tiles
constexpr int SEQP  = 4416;                    // padded V^T row pitch
constexpr size_t SD = (size_t)SEQ * DIM;

typedef float f32x4 __attribute__((ext_vector_type(4)));
typedef short bf16x8 __attribute__((ext_vector_type(8)));
typedef short bf16x4 __attribute__((ext_vector_type(4)));

__device__ inline unsigned short f2bf(float f) {
  union { float f; unsigned u; } x; x.f = f;
  return (unsigned short)((x.u + 0x7FFFu + ((x.u >> 16) & 1u)) >> 16);
}

#define GLD16(g, l)                                                                        \
  __builtin_amdgcn_global_load_lds((const __attribute__((address_space(1))) unsigned*)    \
                                       (const void*)(g),                                  \
                                   (__attribute__((address_space(3))) unsigned*)(void*)(l),\
                                   16, 0, 0)

// ============================================================
// prep: zero attn-map, mask counts, padded float4 mask table
// ============================================================
__global__ __launch_bounds__(256) void prep_kernel(const float* __restrict__ mask,
                                                   float* __restrict__ amap,
                                                   float* __restrict__ cnt,
                                                   float4* __restrict__ msk4) {
  int t = threadIdx.x;
  for (int i = t; i < 2 * SEQ; i += 256) amap[i] = 0.f;
  for (int i = t; i < 512; i += 256) {
    float4 v;
    v.x = (i < XS) ? mask[i] : 0.f;
    v.y = (i < XS) ? mask[XS + i] : 0.f;
    v.z = (i < XS) ? 1.f : 0.f;
    v.w = 0.f;
    msk4[i] = v;
  }
  float c0 = 0.f, c1 = 0.f;
  for (int i = t; i < XS; i += 256) { c0 += mask[i]; c1 += mask[XS + i]; }
  __shared__ float red0[256];
  __shared__ float red1[256];
  red0[t] = c0; red1[t] = c1;
  __syncthreads();
  for (int off = 128; off > 0; off >>= 1) {
    if (t < off) { red0[t] += red0[t + off]; red1[t] += red1[t + off]; }
    __syncthreads();
  }
  if (t == 0) { cnt[0] = red0[0]; cnt[1] = red1[0]; }
}

// zero V^T tail columns (keys SEQ..SEQP)
__global__ __launch_bounds__(256) void padzero(unsigned short* __restrict__ vt) {
  const int pad = SEQP - SEQ;
  const int total = DIM * pad;
  for (int i = blockIdx.x * 256 + threadIdx.x; i < total; i += gridDim.x * 256) {
    const int d = i / pad, c = i - d * pad;
    vt[(size_t)d * SEQP + SEQ + c] = 0;
  }
}

// f32 -> bf16 (RNE), vectorized
__global__ __launch_bounds__(256) void to_bf16(const float* __restrict__ in,
                                               unsigned short* __restrict__ out, int n4) {
  for (int i = blockIdx.x * 256 + threadIdx.x; i < n4; i += gridDim.x * 256) {
    const float4 v = ((const float4*)in)[i];
    ushort4 o;
    o.x = f2bf(v.x); o.y = f2bf(v.y); o.z = f2bf(v.z); o.w = f2bf(v.w);
    ((ushort4*)out)[i] = o;
  }
}

// 4 weight matrices in one launch (z selects)
__global__ __launch_bounds__(256) void to_bf16_w(const float* __restrict__ W0, const float* __restrict__ W1,
                                                 const float* __restrict__ W2, const float* __restrict__ W3,
                                                 unsigned short* __restrict__ o0, unsigned short* __restrict__ o1,
                                                 unsigned short* __restrict__ o2, unsigned short* __restrict__ o3,
                                                 int n4) {
  const int z = blockIdx.z;
  const float* in = (z == 0) ? W0 : (z == 1) ? W1 : (z == 2) ? W2 : W3;
  unsigned short* out = (z == 0) ? o0 : (z == 1) ? o1 : (z == 2) ? o2 : o3;
  for (int i = blockIdx.x * 256 + threadIdx.x; i < n4; i += gridDim.x * 256) {
    const float4 v = ((const float4*)in)[i];
    ushort4 o;
    o.x = f2bf(v.x); o.y = f2bf(v.y); o.z = f2bf(v.z); o.w = f2bf(v.w);
    ((ushort4*)out)[i] = o;
  }
}

// ============================================================
// combined QKV MFMA GEMM (NT): z=0 -> Q f32, z=1 -> K f32, z=2 -> V^T bf16
// ============================================================
__global__ __launch_bounds__(256) void gemm_qkv(const unsigned short* __restrict__ A,
                                                const unsigned short* __restrict__ B0,
                                                const unsigned short* __restrict__ B1,
                                                const unsigned short* __restrict__ B2,
                                                const float* __restrict__ bq,
                                                const float* __restrict__ bk,
                                                const float* __restrict__ bv,
                                                float* __restrict__ o0,
                                                float* __restrict__ o1,
                                                unsigned short* __restrict__ vtout,
                                                int M) {
  __shared__ unsigned short As[128 * 64];
  __shared__ unsigned short Bs[128 * 64];
  const int z = blockIdx.z;
  const unsigned short* B = (z == 0) ? B0 : (z == 1) ? B1 : B2;
  const float* bias = (z == 0) ? bq : (z == 1) ? bk : bv;
  const int t    = threadIdx.x;
  const int lane = t & 63;
  const int w    = t >> 6;
  const int wr   = w >> 1, wc = w & 1;
  const int bm = blockIdx.x * 128, bn = blockIdx.y * 128;
  const int lq = lane & 15, lg = lane >> 4;
  f32x4 acc[4][4] = {};
  for (int k0 = 0; k0 < DIM; k0 += 64) {
#pragma unroll
    for (int i = 0; i < 4; ++i) {
      const int idx = i * 256 + t;
      const int row = idx >> 3;
      const int c8  = (idx & 7) * 8;
      const int ga  = min(bm + row, M - 1);
      GLD16(A + (size_t)ga * DIM + k0 + c8, As + idx * 8);
      const int gb  = bn + row;
      GLD16(B + (size_t)gb * DIM + k0 + c8, Bs + idx * 8);
    }
    __syncthreads();
#pragma unroll
    for (int kk = 0; kk < 2; ++kk) {
      bf16x8 af[4], bf[4];
#pragma unroll
      for (int m = 0; m < 4; ++m)
        af[m] = *(const bf16x8*)(As + (wr * 64 + m * 16 + lq) * 64 + kk * 32 + lg * 8);
#pragma unroll
      for (int n = 0; n < 4; ++n)
        bf[n] = *(const bf16x8*)(Bs + (wc * 64 + n * 16 + lq) * 64 + kk * 32 + lg * 8);
#pragma unroll
      for (int m = 0; m < 4; ++m)
#pragma unroll
        for (int n = 0; n < 4; ++n)
          acc[m][n] = __builtin_amdgcn_mfma_f32_16x16x32_bf16(af[m], bf[n], acc[m][n], 0, 0, 0);
    }
    __syncthreads();
  }
#pragma unroll
  for (int n = 0; n < 4; ++n) {
    const int col = bn + wc * 64 + n * 16 + lq;
    const float bv2 = bias[col];
#pragma unroll
    for (int m = 0; m < 4; ++m) {
      const int rm = bm + wr * 64 + m * 16 + lg * 4;
      if (z < 2) {
        float* C = (z == 0) ? o0 : o1;
#pragma unroll
        for (int r = 0; r < 4; ++r) {
          const int row = rm + r;
          if (row < M) C[(size_t)row * DIM + col] = acc[m][n][r] + bv2;
        }
      } else {
        if (rm < M) {
          bf16x4 o;
#pragma unroll
          for (int r = 0; r < 4; ++r) o[r] = (short)f2bf(acc[m][n][r] + bv2);
          *(bf16x4*)(vtout + (size_t)col * SEQP + rm) = o;
        }
      }
    }
  }
}

// ============================================================
// single-output GEMM for the final projection (f32 out)
// ============================================================
__global__ __launch_bounds__(256) void gemm_mfma(const unsigned short* __restrict__ A,
                                                 const unsigned short* __restrict__ B,
                                                 const float* __restrict__ bias,
                                                 float* __restrict__ C, int M) {
  __shared__ unsigned short As[128 * 64];
  __shared__ unsigned short Bs[128 * 64];
  const int t    = threadIdx.x;
  const int lane = t & 63;
  const int w    = t >> 6;
  const int wr   = w >> 1, wc = w & 1;
  const int bm = blockIdx.x * 128, bn = blockIdx.y * 128;
  const int lq = lane & 15, lg = lane >> 4;
  f32x4 acc[4][4] = {};
  for (int k0 = 0; k0 < DIM; k0 += 64) {
#pragma unroll
    for (int i = 0; i < 4; ++i) {
      const int idx = i * 256 + t;
      const int row = idx >> 3;
      const int c8  = (idx & 7) * 8;
      const int ga  = min(bm + row, M - 1);
      GLD16(A + (size_t)ga * DIM + k0 + c8, As + idx * 8);
      const int gb  = bn + row;
      GLD16(B + (size_t)gb * DIM + k0 + c8, Bs + idx * 8);
    }
    __syncthreads();
#pragma unroll
    for (int kk = 0; kk < 2; ++kk) {
      bf16x8 af[4], bf[4];
#pragma unroll
      for (int m = 0; m < 4; ++m)
        af[m] = *(const bf16x8*)(As + (wr * 64 + m * 16 + lq) * 64 + kk * 32 + lg * 8);
#pragma unroll
      for (int n = 0; n < 4; ++n)
        bf[n] = *(const bf16x8*)(Bs + (wc * 64 + n * 16 + lq) * 64 + kk * 32 + lg * 8);
#pragma unroll
      for (int m = 0; m < 4; ++m)
#pragma unroll
        for (int n = 0; n < 4; ++n)
          acc[m][n] = __builtin_amdgcn_mfma_f32_16x16x32_bf16(af[m], bf[n], acc[m][n], 0, 0, 0);
    }
    __syncthreads();
  }
#pragma unroll
  for (int n = 0; n < 4; ++n) {
    const int col = bn + wc * 64 + n * 16 + lq;
    const float bv = bias[col];
#pragma unroll
    for (int m = 0; m < 4; ++m) {
      const int rm = bm + wr * 64 + m * 16 + lg * 4;
#pragma unroll
      for (int r = 0; r < 4; ++r) {
        const int row = rm + r;
        if (row < M) C[(size_t)row * DIM + col] = acc[m][n][r] + bv;
      }
    }
  }
}

// ============================================================
// RMSNorm + RoPE for Q and K in one launch (blockIdx.y selects)
// ============================================================
__global__ __launch_bounds__(256) void rms_rope2(const float* __restrict__ qy,
                                                 const float* __restrict__ ky,
                                                 const float* __restrict__ gq,
                                                 const float* __restrict__ gk,
                                                 const float* __restrict__ fcos,
                                                 const float* __restrict__ fsin,
                                                 unsigned short* __restrict__ qout,
                                                 unsigned short* __restrict__ kout) {
  const int z = blockIdx.y;
  const float* y = z ? ky : qy;
  const float* g = z ? gk : gq;
  unsigned short* outb = z ? kout : qout;
  const float scale = z ? 1.0f : 0.08838834764831845f;  // 1/sqrt(128) folded into q
  const int s = blockIdx.x;
  const float* row = y + (size_t)s * DIM;
  const int t = threadIdx.x;
  float ss = 0.f;
  for (int i = t; i < DIM / 4; i += 256) {
    const float4 v = ((const float4*)row)[i];
    ss += v.x * v.x + v.y * v.y + v.z * v.z + v.w * v.w;
  }
#pragma unroll
  for (int off = 1; off < 64; off <<= 1) ss += __shfl_xor(ss, off);
  __shared__ float wred[4];
  if ((t & 63) == 0) wred[t >> 6] = ss;
  __syncthreads();
  const float tot = wred[0] + wred[1] + wred[2] + wred[3];
  const float rs = rsqrtf(tot * (1.0f / DIM) + 1e-6f);
  const int fi  = s / HHWW;
  const int rem = s - fi * HHWW;
  const int hi  = rem / WWc;
  const int wi  = rem - hi * WWc;
  for (int p = t; p < DIM / 2; p += 256) {
    const int head = p >> 6;
    const int c    = p & 63;
    const int idx  = head * HD + 2 * c;
    const int trow = (c < C0c) ? fi : ((c < C0c + C1c) ? hi : wi);
    const float co = fcos[trow * CH + c];
    const float si = fsin[trow * CH + c];
    const float a  = row[idx] * rs * g[idx];
    const float b  = row[idx + 1] * rs * g[idx + 1];
    ushort2 pr;
    pr.x = f2bf((a * co - b * si) * scale);
    pr.y = f2bf((a * si + b * co) * scale);
    *(ushort2*)(outb + (size_t)s * DIM + idx) = pr;
  }
}

// ============================================================
// Flash attention v6: FIXED ZERO softmax frame.
// |s| <= |q||k| ~ 12 (rmsnorm + folded 1/sqrt(128)) => exp(s) safe in
// f32/bf16 with no max tracking: no shfl, no rescale, no branch in the
// KV loop. Per-lane partial l/d2/n0/n1, reduced once in epilogue.
// 32 q/wave, KVB=32 double-buffered K+V via global_load_lds.
// ============================================================
#define SOFT_QS(QS, SACC, MAP_, LAST_, KBV)                                                \
  {                                                                                        \
    float sv[8];                                                                           \
    _Pragma("unroll")                                                                      \
    for (int i = 0; i < 8; ++i) {                                                          \
      float v = SACC[i >> 2][i & 3];                                                       \
      if (LAST_) { const int key = (KBV) + (i >> 2) * 16 + lg * 4 + (i & 3);               \
                   if (key >= SEQ) v = -1e30f; }                                           \
      sv[i] = __expf(v);                                                                   \
      ls[QS] += sv[i];                                                                     \
    }                                                                                      \
    if (MAP_) {                                                                            \
      _Pragma("unroll")                                                                    \
      for (int i = 0; i < 8; ++i) {                                                        \
        const int key = (KBV) + (i >> 2) * 16 + lg * 4 + (i & 3);                          \
        const float4 mv = Msk[key];                                                        \
        n0[QS] = fmaf(sv[i], mv.x, n0[QS]);                                                \
        n1[QS] = fmaf(sv[i], mv.y, n1[QS]);                                                \
        d2[QS] = fmaf(sv[i], mv.z, d2[QS]);                                                \
      }                                                                                    \
    }                                                                                      \
    _Pragma("unroll")                                                                      \
    for (int kbi = 0; kbi < 2; ++kbi) {                                                    \
      unsigned r0, r1;                                                                     \
      asm("v_cvt_pk_bf16_f32 %0, %1, %2" : "=v"(r0) : "v"(sv[kbi*4+0]), "v"(sv[kbi*4+1])); \
      asm("v_cvt_pk_bf16_f32 %0, %1, %2" : "=v"(r1) : "v"(sv[kbi*4+2]), "v"(sv[kbi*4+3])); \
      uint2 pw; pw.x = r0; pw.y = r1;                                                      \
      *(uint2*)&Pw[QS][lq][kbi * 16 + lg * 4] = pw;                                        \
    }                                                                                      \
  }

#define TILE_BODY(KB_, MAP_, LAST_, PRE_)                                                  \
  {                                                                                        \
    const int kb_ = (KB_);                                                                 \
    const int cur_ = (kb_ >> 5) & 1;                                                       \
    const unsigned short* Kc = Ks[cur_];                                                   \
    const unsigned short* Vc = Vs[cur_];                                                   \
    if (PRE_) {                                                                            \
      unsigned short* Kn = Ks[cur_ ^ 1];                                                   \
      unsigned short* Vn = Vs[cur_ ^ 1];                                                   \
      const int kbn = kb_ + KVB;                                                           \
      _Pragma("unroll")                                                                    \
      for (int j = 0; j < 2; ++j) {                                                        \
        const int ck = t + j * 256;                                                        \
        const int kr = ck >> 4, ksl = ck & 15;                                             \
        GLD16(kh + (size_t)min(kbn + kr, SEQ - 1) * DIM + ((ksl ^ (kr & 7)) * 8),          \
              Kn + ck * 8);                                                                \
        const int vd = ck >> 2, vsl = ck & 3;                                              \
        GLD16(vh + (size_t)vd * SEQP + kbn + ((vsl ^ ((vd >> 1) & 3)) * 8),                \
              Vn + ck * 8);                                                                \
      }                                                                                    \
    }                                                                                      \
    f32x4 sacc0[2] = {}, sacc1[2] = {};                                                    \
    _Pragma("unroll")                                                                      \
    for (int kbi = 0; kbi < 2; ++kbi) {                                                    \
      const int krow = kbi * 16 + lq;                                                      \
      _Pragma("unroll")                                                                    \
      for (int c = 0; c < 4; ++c) {                                                        \
        const bf16x8 kf = *(const bf16x8*)(Kc + (krow * 16 + ((c * 4 + lg) ^ (krow & 7))) * 8); \
        sacc0[kbi] = __builtin_amdgcn_mfma_f32_16x16x32_bf16(kf, qf0[c], sacc0[kbi], 0, 0, 0);  \
        sacc1[kbi] = __builtin_amdgcn_mfma_f32_16x16x32_bf16(kf, qf1[c], sacc1[kbi], 0, 0, 0);  \
      }                                                                                    \
    }                                                                                      \
    SOFT_QS(0, sacc0, MAP_, LAST_, kb_)                                                    \
    SOFT_QS(1, sacc1, MAP_, LAST_, kb_)                                                    \
    {                                                                                      \
      const bf16x8 pf0 = *(const bf16x8*)&Pw[0][lq][lg * 8];                               \
      const bf16x8 pf1 = *(const bf16x8*)&Pw[1][lq][lg * 8];                               \
      _Pragma("unroll")                                                                    \
      for (int db = 0; db < 8; ++db) {                                                     \
        const int vd = db * 16 + lq;                                                       \
        const bf16x8 vf = *(const bf16x8*)(Vc + (vd * 4 + (lg ^ ((vd >> 1) & 3))) * 8);    \
        acc0[db] = __builtin_amdgcn_mfma_f32_16x16x32_bf16(vf, pf0, acc0[db], 0, 0, 0);    \
        acc1[db] = __builtin_amdgcn_mfma_f32_16x16x32_bf16(vf, pf1, acc1[db], 0, 0, 0);    \
      }                                                                                    \
    }                                                                                      \
    if (PRE_) __syncthreads();                                                             \
  }

__global__ __launch_bounds__(256, 3) void flash_mfma(const unsigned short* __restrict__ qbuf,
                                                     const unsigned short* __restrict__ kbuf,
                                                     const unsigned short* __restrict__ vt,
                                                     const float4* __restrict__ msk4,
                                                     const float* __restrict__ cnt,
                                                     unsigned short* __restrict__ ob,
                                                     float* __restrict__ amap) {
  const int h    = blockIdx.y;
  const int t    = threadIdx.x;
  const int w    = t >> 6;
  const int lane = t & 63;
  const int lq   = lane & 15, lg = lane >> 4;
  const int qbase = blockIdx.x * 128 + w * 32;

  __shared__ __align__(16) unsigned short Ks[2][KVB * 128];  // [key][16 chunks], src-swizzled
  __shared__ __align__(16) unsigned short Vs[2][128 * KVB];  // [dim][4 chunks],  src-swizzled
  __shared__ __align__(16) unsigned short Plds[4][2][16][40];
  __shared__ float4 Msk[512];
  unsigned short (*Pw)[16][40] = Plds[w];

  const unsigned short* kh = kbuf + h * HD;
  const unsigned short* vh = vt + (size_t)(h * HD) * SEQP;

  for (int i = t; i < 512; i += 256) Msk[i] = msk4[i];

  const int qsrc0 = min(qbase + lq, SEQ - 1);
  const int qsrc1 = min(qbase + 16 + lq, SEQ - 1);
  bf16x8 qf0[4], qf1[4];
#pragma unroll
  for (int c = 0; c < 4; ++c) {
    qf0[c] = *(const bf16x8*)(qbuf + (size_t)qsrc0 * DIM + h * HD + c * 32 + lg * 8);
    qf1[c] = *(const bf16x8*)(qbuf + (size_t)qsrc1 * DIM + h * HD + c * 32 + lg * 8);
  }

  f32x4 acc0[8] = {}, acc1[8] = {};
  float ls[2] = {0.f, 0.f};
  float d2[2] = {0.f, 0.f}, n0[2] = {0.f, 0.f}, n1[2] = {0.f, 0.f};

  // prologue: stage tile 0 into buffer 0
#pragma unroll
  for (int j = 0; j < 2; ++j) {
    const int ck = t + j * 256;
    const int kr = ck >> 4, ksl = ck & 15;
    GLD16(kh + (size_t)min(kr, SEQ - 1) * DIM + ((ksl ^ (kr & 7)) * 8), Ks[0] + ck * 8);
    const int vd = ck >> 2, vsl = ck & 3;
    GLD16(vh + (size_t)vd * SEQP + ((vsl ^ ((vd >> 1) & 3)) * 8), Vs[0] + ck * 8);
  }
  __syncthreads();

  for (int tile = 0; tile < 16; ++tile)         TILE_BODY(tile * KVB, true,  false, true);
  for (int tile = 16; tile < NT - 1; ++tile)    TILE_BODY(tile * KVB, false, false, true);
  TILE_BODY((NT - 1) * KVB, false, true, false);

  // epilogue: reduce per-lane l across the 4 lane-groups, write O
#pragma unroll
  for (int qs = 0; qs < 2; ++qs) {
    ls[qs] += __shfl_xor(ls[qs], 16);
    ls[qs] += __shfl_xor(ls[qs], 32);
  }
  {
    const int qrow = qbase + lq;
    if (qrow < SEQ) {
      const float inv = 1.f / ls[0];
#pragma unroll
      for (int db = 0; db < 8; ++db) {
        bf16x4 o;
#pragma unroll
        for (int r = 0; r < 4; ++r) o[r] = (short)f2bf(acc0[db][r] * inv);
        *(bf16x4*)(ob + (size_t)qrow * DIM + h * HD + db * 16 + lg * 4) = o;
      }
    }
  }
  {
    const int qrow = qbase + 16 + lq;
    if (qrow < SEQ) {
      const float inv = 1.f / ls[1];
#pragma unroll
      for (int db = 0; db < 8; ++db) {
        bf16x4 o;
#pragma unroll
        for (int r = 0; r < 4; ++r) o[r] = (short)f2bf(acc1[db][r] * inv);
        *(bf16x4*)(ob + (size_t)qrow * DIM + h * HD + db * 16 + lg * 4) = o;
      }
    }
  }
  // attn-map: same fixed frame everywhere -> plain sums
#pragma unroll
  for (int qs = 0; qs < 2; ++qs) {
    float dd = d2[qs], a0 = n0[qs], a1 = n1[qs];
    dd += __shfl_xor(dd, 16); dd += __shfl_xor(dd, 32);
    a0 += __shfl_xor(a0, 16); a0 += __shfl_xor(a0, 32);
    a1 += __shfl_xor(a1, 16); a1 += __shfl_xor(a1, 32);
    const int qrow = qbase + qs * 16 + lq;
    if (lane < 16 && qrow < SEQ) {
      const float invd = 1.f / (dd * (float)HEADS);
      atomicAdd(&amap[qrow],       a0 * invd / cnt[0]);
      atomicAdd(&amap[SEQ + qrow], a1 * invd / cnt[1]);
    }
  }
}

// ============================================================
extern "C" void kernel_launch(void* const* d_in, const int* in_sizes, int n_in,
                              void* d_out, int out_size, void* d_ws, size_t ws_size,
                              hipStream_t stream) {
  const float* x    = (const float*)d_in[0];
  const float* Wq   = (const float*)d_in[1];
  const float* bq   = (const float*)d_in[2];
  const float* Wk   = (const float*)d_in[3];
  const float* bk   = (const float*)d_in[4];
  const float* Wv   = (const float*)d_in[5];
  const float* bv   = (const float*)d_in[6];
  const float* Wo   = (const float*)d_in[7];
  const float* bo   = (const float*)d_in[8];
  const float* gq   = (const float*)d_in[9];
  const float* gk   = (const float*)d_in[10];
  const float* fc   = (const float*)d_in[11];
  const float* fs   = (const float*)d_in[12];
  const float* mask = (const float*)d_in[13];

  float* out  = (float*)d_out;
  float* amap = out + SD;
  float* f32a = out;                                    // Q f32 scratch in d_out

  float* f32b        = (float*)d_ws;                    // SD f32 (K); later ob
  unsigned short* xb = (unsigned short*)(f32b + SD);    // SD bf16
  unsigned short* qb = xb + SD;
  unsigned short* kb = qb + SD;
  unsigned short* vt = kb + SD;                         // DIM*SEQP bf16
  unsigned short* wqb = vt + (size_t)DIM * SEQP;        // 4x DIM*DIM bf16
  unsigned short* wkb = wqb + (size_t)DIM * DIM;
  unsigned short* wvb = wkb + (size_t)DIM * DIM;
  unsigned short* wob = wvb + (size_t)DIM * DIM;
  float4* msk4 = (float4*)(wob + (size_t)DIM * DIM);    // 512
  float* cnt  = (float*)(msk4 + 512);
  unsigned short* ob = (unsigned short*)f32b;           // alias: f32b dead by then

  prep_kernel<<<1, 256, 0, stream>>>(mask, amap, cnt, msk4);
  padzero<<<64, 256, 0, stream>>>(vt);
  to_bf16<<<2048, 256, 0, stream>>>(x, xb, (int)(SD / 4));
  constexpr int W4 = DIM * DIM / 4;
  to_bf16_w<<<dim3(512, 1, 4), 256, 0, stream>>>(Wq, Wk, Wv, Wo, wqb, wkb, wvb, wob, W4);

  const dim3 gg((SEQ + 127) / 128, DIM / 128, 3);
  gemm_qkv<<<gg, 256, 0, stream>>>(xb, wqb, wkb, wvb, bq, bk, bv, f32a, f32b, vt, SEQ);

  rms_rope2<<<dim3(SEQ, 2), 256, 0, stream>>>(f32a, f32b, gq, gk, fc, fs, qb, kb);

  const dim3 fg((SEQ + 127) / 128, HEADS);
  flash_mfma<<<fg, 256, 0, stream>>>(qb, kb, vt, msk4, cnt, ob, amap);

  const dim3 go((SEQ + 127) / 128, DIM / 128);
  gemm_mfma<<<go, 256, 0, stream>>>(ob, wob, bo, out, SEQ);
}